// Round 1
// baseline (528.030 us; speedup 1.0000x reference)
//
#include <hip/hip_runtime.h>

typedef unsigned short u16;
typedef __attribute__((ext_vector_type(8))) short s8v;
typedef __attribute__((ext_vector_type(4))) short s4v;
typedef __attribute__((ext_vector_type(4))) float f4v;

// Problem constants: H=W=64, WS=8, D=512, CF=128, INC=640, HEAD=8, DH=64
// tokens = 8*4096 = 32768 window tokens, +512 global (conv) tokens
#define NTOK 32768

__device__ __forceinline__ float bf2f(u16 u){
  union { unsigned int i; float f; } p; p.i = ((unsigned int)u) << 16; return p.f;
}
__device__ __forceinline__ u16 f2bf(float f){   // RNE
  union { float f; unsigned int i; } p; p.f = f;
  unsigned int r = p.i + 0x7FFFu + ((p.i >> 16) & 1u);
  return (u16)(r >> 16);
}
__device__ __forceinline__ int wtok_idx(int b, int gh, int gw, int n){
  return b*4096 + (gh*8 + (n>>3))*64 + gw*8 + (n&7);
}

// ---------------- weight prep: bf16 convert + LN-gain fold ----------------
__global__ __launch_bounds__(256) void prep_weights(
    const float* __restrict__ rww, const float* __restrict__ wq,
    const float* __restrict__ wk,  const float* __restrict__ wv,
    const float* __restrict__ wo,  const float* __restrict__ qng,
    const float* __restrict__ kng, const float* __restrict__ vng,
    u16* __restrict__ orw, u16* __restrict__ oq, u16* __restrict__ ok,
    u16* __restrict__ ov,  u16* __restrict__ oo)
{
  int i = blockIdx.x*256 + threadIdx.x;
  if (i < 409600){ orw[i] = f2bf(rww[i]); return; }
  i -= 409600;
  if (i < 327680){ oq[i] = f2bf(wq[i] * qng[i % 640]); return; }
  i -= 327680;
  if (i < 327680){ ok[i] = f2bf(wk[i] * kng[i % 640]); return; }
  i -= 327680;
  if (i < 262144){ ov[i] = f2bf(wv[i] * vng[i & 511]); return; }
  i -= 262144;
  oo[i] = f2bf(wo[i]);
}

// bias fold: b'_o = b_o + sum_i ln_b[i] * W[o,i]
__global__ __launch_bounds__(256) void prep_bias(
    const float* __restrict__ wq, const float* __restrict__ bq, const float* __restrict__ qnb,
    const float* __restrict__ wk, const float* __restrict__ bk, const float* __restrict__ knb,
    const float* __restrict__ wv, const float* __restrict__ bv, const float* __restrict__ vnb,
    float* __restrict__ obq, float* __restrict__ obk, float* __restrict__ obv)
{
  int o = blockIdx.x*256 + threadIdx.x;  // 0..1535
  int which = o >> 9;
  int oo = o & 511;
  if (which == 0){
    float s = bq[oo];
    for (int i=0;i<640;i++) s += qnb[i]*wq[oo*640+i];
    obq[oo] = s;
  } else if (which == 1){
    float s = bk[oo];
    for (int i=0;i<640;i++) s += knb[i]*wk[oo*640+i];
    obk[oo] = s;
  } else {
    float s = bv[oo];
    for (int i=0;i<512;i++) s += vnb[i]*wv[oo*512+i];
    obv[oo] = s;
  }
}

// ---------------- build qk = concat(x,f) as bf16 [32768][640] ----------------
__global__ __launch_bounds__(256) void build_qk(
    const float* __restrict__ X, const float* __restrict__ F, u16* __restrict__ qkb)
{
  int idx = blockIdx.x*256 + threadIdx.x;      // 32768*160 threads exactly
  int token = idx / 160;
  int c4 = (idx - token*160) * 4;
  f4v v;
  if (c4 < 512) v = *(const f4v*)(X + (size_t)token*512 + c4);
  else          v = *(const f4v*)(F + (size_t)token*128 + (c4 - 512));
  s4v o;
  #pragma unroll
  for (int j=0;j<4;j++) o[j] = (short)f2bf(v[j]);
  *(s4v*)(qkb + (size_t)token*640 + c4) = o;
}

// ---------------- GEMM: C[M,N] = A[M,K](bf16) * W[N,K](bf16)^T, + epilogue ----
// EPI 0: out_bf16 = acc + bias
// EPI 1: reweight: out_bf16 = qk_f32(col) * sigmoid(acc + bias)
// EPI 2: out_f32 = acc + bias
template<int EPI>
__global__ __launch_bounds__(256, 3) void gemm_kernel(
    const u16* __restrict__ A, const u16* __restrict__ B,
    const float* __restrict__ bias,
    u16* __restrict__ outb, float* __restrict__ outf,
    const float* __restrict__ Xr, const float* __restrict__ Fr,
    int N, int K)
{
  __shared__ u16 lA[128*64];
  __shared__ u16 lB[128*64];
  const int tid = threadIdx.x;
  const int lane = tid & 63;
  const int w = tid >> 6;
  const int wm = (w >> 1) * 64;
  const int wn = (w & 1) * 64;
  const int nb = N >> 7;
  const int m0 = (blockIdx.x / nb) << 7;
  const int n0 = (blockIdx.x % nb) << 7;

  const f4v fzero = {0.f, 0.f, 0.f, 0.f};
  f4v acc[4][4];
  #pragma unroll
  for (int i=0;i<4;i++)
    #pragma unroll
    for (int j=0;j<4;j++) acc[i][j] = fzero;

  for (int k0 = 0; k0 < K; k0 += 64){
    // stage A,B tiles [128 rows][64 k] with chunk-XOR swizzle (chunk ^= row&7)
    #pragma unroll
    for (int it=0; it<4; it++){
      int s = it*256 + tid;
      int row = s >> 3, c = s & 7;
      s8v va = *(const s8v*)(A + (size_t)(m0+row)*K + k0 + c*8);
      *(s8v*)&lA[(row*8 + (c ^ (row&7)))*8] = va;
      s8v vb = *(const s8v*)(B + (size_t)(n0+row)*K + k0 + c*8);
      *(s8v*)&lB[(row*8 + (c ^ (row&7)))*8] = vb;
    }
    __syncthreads();
    #pragma unroll
    for (int kk=0; kk<2; kk++){
      const int cg = kk*4 + (lane>>4);
      s8v bfr[4];
      #pragma unroll
      for (int ni=0; ni<4; ni++){
        int col = wn + ni*16 + (lane&15);
        bfr[ni] = *(const s8v*)&lB[(col*8 + (cg ^ (col&7)))*8];
      }
      #pragma unroll
      for (int mi=0; mi<4; mi++){
        int row = wm + mi*16 + (lane&15);
        s8v afr = *(const s8v*)&lA[(row*8 + (cg ^ (row&7)))*8];
        #pragma unroll
        for (int ni=0; ni<4; ni++)
          acc[mi][ni] = __builtin_amdgcn_mfma_f32_16x16x32_bf16(afr, bfr[ni], acc[mi][ni], 0, 0, 0);
      }
    }
    __syncthreads();
  }

  #pragma unroll
  for (int mi=0; mi<4; mi++){
    #pragma unroll
    for (int ni=0; ni<4; ni++){
      const int colg = n0 + wn + ni*16 + (lane&15);
      const float bb = bias[colg];
      #pragma unroll
      for (int j=0;j<4;j++){
        const int rowg = m0 + wm + mi*16 + (lane>>4)*4 + j;
        float v = acc[mi][ni][j] + bb;
        if constexpr (EPI == 0){
          outb[(size_t)rowg*N + colg] = f2bf(v);
        } else if constexpr (EPI == 1){
          float sg = 1.f / (1.f + __expf(-v));
          float qv = (colg < 512) ? Xr[(size_t)rowg*512 + colg]
                                  : Fr[(size_t)rowg*128 + (colg - 512)];
          outb[(size_t)rowg*N + colg] = f2bf(qv * sg);
        } else {
          outf[(size_t)rowg*N + colg] = v;
        }
      }
    }
  }
}

// ---------------- LN (no affine; folded into weights) ----------------
// one wave per token over 640 bf16 channels
__global__ __launch_bounds__(256) void ln_qk_kernel(const u16* __restrict__ y, u16* __restrict__ u)
{
  int token = blockIdx.x*4 + (threadIdx.x >> 6);
  int lane = threadIdx.x & 63;
  const u16* row = y + (size_t)token*640;
  float v[10], s = 0.f, s2 = 0.f;
  #pragma unroll
  for (int i=0;i<10;i++){ float x = bf2f(row[i*64+lane]); v[i]=x; s+=x; s2+=x*x; }
  #pragma unroll
  for (int m=1;m<64;m<<=1){ s += __shfl_xor(s,m); s2 += __shfl_xor(s2,m); }
  float mean = s*(1.f/640.f);
  float var = s2*(1.f/640.f) - mean*mean;
  float rstd = rsqrtf(var + 1e-5f);
  u16* ur = u + (size_t)token*640;
  #pragma unroll
  for (int i=0;i<10;i++) ur[i*64+lane] = f2bf((v[i]-mean)*rstd);
}

// one wave per token over 512 f32 channels (x -> V-path input)
__global__ __launch_bounds__(256) void ln_x_kernel(const float* __restrict__ X, u16* __restrict__ uv)
{
  int token = blockIdx.x*4 + (threadIdx.x >> 6);
  int lane = threadIdx.x & 63;
  const float* row = X + (size_t)token*512;
  float v[8], s = 0.f, s2 = 0.f;
  #pragma unroll
  for (int i=0;i<8;i++){ float x = row[i*64+lane]; v[i]=x; s+=x; s2+=x*x; }
  #pragma unroll
  for (int m=1;m<64;m<<=1){ s += __shfl_xor(s,m); s2 += __shfl_xor(s2,m); }
  float mean = s*(1.f/512.f);
  float var = s2*(1.f/512.f) - mean*mean;
  float rstd = rsqrtf(var + 1e-5f);
  u16* ur = uv + (size_t)token*512;
  #pragma unroll
  for (int i=0;i<8;i++) ur[i*64+lane] = f2bf((v[i]-mean)*rstd);
}

// ---------------- depthwise 8x8 stride-8 conv + LN, writes global-token rows ----
__global__ __launch_bounds__(640) void convk_ln_kernel(
    const u16* __restrict__ qkrw, const float* __restrict__ cw,
    const float* __restrict__ cb, u16* __restrict__ u)
{
  int bg = blockIdx.x;               // b*64 + gpos
  int b = bg >> 6, gpos = bg & 63;
  int gh = gpos >> 3, gw = gpos & 7;
  int ch = threadIdx.x;              // 0..639
  int base = b*4096 + gh*8*64 + gw*8;
  float acc = cb[ch];
  #pragma unroll
  for (int r=0;r<8;r++)
    #pragma unroll
    for (int c=0;c<8;c++)
      acc += bf2f(qkrw[(size_t)(base + r*64 + c)*640 + ch]) * cw[ch*64 + r*8 + c];
  float s = acc, s2 = acc*acc;
  #pragma unroll
  for (int m=1;m<64;m<<=1){ s += __shfl_xor(s,m); s2 += __shfl_xor(s2,m); }
  __shared__ float rs[10], rs2[10];
  int wid = threadIdx.x >> 6, lane = threadIdx.x & 63;
  if (lane == 0){ rs[wid] = s; rs2[wid] = s2; }
  __syncthreads();
  float ts = 0.f, ts2 = 0.f;
  #pragma unroll
  for (int i=0;i<10;i++){ ts += rs[i]; ts2 += rs2[i]; }
  float mean = ts*(1.f/640.f);
  float var = ts2*(1.f/640.f) - mean*mean;
  float rstd = rsqrtf(var + 1e-5f);
  u[(size_t)(NTOK + bg)*640 + ch] = f2bf((acc-mean)*rstd);
}

__global__ __launch_bounds__(512) void convv_ln_kernel(
    const float* __restrict__ X, const float* __restrict__ cw,
    const float* __restrict__ cb, u16* __restrict__ uv)
{
  int bg = blockIdx.x;
  int b = bg >> 6, gpos = bg & 63;
  int gh = gpos >> 3, gw = gpos & 7;
  int ch = threadIdx.x;              // 0..511
  int base = b*4096 + gh*8*64 + gw*8;
  float acc = cb[ch];
  #pragma unroll
  for (int r=0;r<8;r++)
    #pragma unroll
    for (int c=0;c<8;c++)
      acc += X[(size_t)(base + r*64 + c)*512 + ch] * cw[ch*64 + r*8 + c];
  float s = acc, s2 = acc*acc;
  #pragma unroll
  for (int m=1;m<64;m<<=1){ s += __shfl_xor(s,m); s2 += __shfl_xor(s2,m); }
  __shared__ float rs[8], rs2[8];
  int wid = threadIdx.x >> 6, lane = threadIdx.x & 63;
  if (lane == 0){ rs[wid] = s; rs2[wid] = s2; }
  __syncthreads();
  float ts = 0.f, ts2 = 0.f;
  #pragma unroll
  for (int i=0;i<8;i++){ ts += rs[i]; ts2 += rs2[i]; }
  float mean = ts*(1.f/512.f);
  float var = ts2*(1.f/512.f) - mean*mean;
  float rstd = rsqrtf(var + 1e-5f);
  uv[(size_t)(NTOK + bg)*512 + ch] = f2bf((acc-mean)*rstd);
}

// ---------------- attention per (b, window, head) ----------------
// Q 64x64, K/V 128x64 (64 window + 64 global tokens). S=QK^T via MFMA,
// f32 softmax (no max-subtract: |scores| small), P through LDS, PV via MFMA.
__global__ __launch_bounds__(256, 2) void attn_kernel(
    const u16* __restrict__ Qp, const u16* __restrict__ Kp,
    const u16* __restrict__ Vp, u16* __restrict__ Out)
{
  int blk = blockIdx.x;                 // b*512 + g*8 + h
  int h = blk & 7, g = (blk >> 3) & 63, b = blk >> 9;
  int gh = g >> 3, gw = g & 7;
  int tid = threadIdx.x, lane = tid & 63, wvid = tid >> 6;

  __shared__ u16 qs[64*64];    // [q][d], 8 chunks/row, swz ^(row&7)
  __shared__ u16 ks[128*64];   // [ktok][d], 8 chunks/row, swz ^(row&7)
  __shared__ u16 vt[64*128];   // V transposed: [d][ktok], 16 chunks/row, swz ^(d&15)
  __shared__ u16 ps[64*128];   // P: [q][ktok], 16 chunks/row, swz ^(q&15)
  __shared__ float red[4][64];

  for (int s = tid; s < 512; s += 256){
    int row = s >> 3, c = s & 7;
    const u16* src = Qp + (size_t)wtok_idx(b,gh,gw,row)*512 + h*64 + c*8;
    *(s8v*)&qs[(row*8 + (c ^ (row&7)))*8] = *(const s8v*)src;
  }
  for (int s = tid; s < 1024; s += 256){
    int row = s >> 3, c = s & 7;
    int t = (row < 64) ? wtok_idx(b,gh,gw,row) : (NTOK + b*64 + (row-64));
    *(s8v*)&ks[(row*8 + (c ^ (row&7)))*8] = *(const s8v*)(Kp + (size_t)t*512 + h*64 + c*8);
  }
  for (int s = tid; s < 1024; s += 256){
    int tokr = s >> 3, c = s & 7;
    int t = (tokr < 64) ? wtok_idx(b,gh,gw,tokr) : (NTOK + b*64 + (tokr-64));
    s8v vv = *(const s8v*)(Vp + (size_t)t*512 + h*64 + c*8);
    #pragma unroll
    for (int j=0;j<8;j++){
      int d = c*8 + j;
      int ck = (tokr >> 3) ^ (d & 15);
      vt[d*128 + ck*8 + (tokr & 7)] = (u16)vv[j];
    }
  }
  __syncthreads();

  // S = Q K^T ; wave wvid owns k-cols [wvid*32, wvid*32+32)
  const f4v fzero = {0.f,0.f,0.f,0.f};
  f4v sacc[4][2];
  #pragma unroll
  for (int i=0;i<4;i++){ sacc[i][0]=fzero; sacc[i][1]=fzero; }
  #pragma unroll
  for (int kk=0; kk<2; kk++){
    const int cg = kk*4 + (lane>>4);
    s8v bfr[2];
    #pragma unroll
    for (int ni=0; ni<2; ni++){
      int col = wvid*32 + ni*16 + (lane&15);
      bfr[ni] = *(const s8v*)&ks[(col*8 + (cg ^ (col&7)))*8];
    }
    #pragma unroll
    for (int mi=0; mi<4; mi++){
      int row = mi*16 + (lane&15);
      s8v afr = *(const s8v*)&qs[(row*8 + (cg ^ (row&7)))*8];
      #pragma unroll
      for (int ni=0; ni<2; ni++)
        sacc[mi][ni] = __builtin_amdgcn_mfma_f32_16x16x32_bf16(afr, bfr[ni], sacc[mi][ni], 0,0,0);
    }
  }

  // exp(S/8) and per-row partial sums over this wave's 32 cols
  float pex[4][2][4];
  float psum[4][4];
  #pragma unroll
  for (int mi=0; mi<4; mi++){
    #pragma unroll
    for (int j=0;j<4;j++){
      float t0 = 0.f;
      #pragma unroll
      for (int ni=0; ni<2; ni++){
        float e = __expf(sacc[mi][ni][j] * 0.125f);
        pex[mi][ni][j] = e;
        t0 += e;
      }
      #pragma unroll
      for (int m=1;m<16;m<<=1) t0 += __shfl_xor(t0, m);
      psum[mi][j] = t0;
    }
  }
  if ((lane & 15) == 0){
    #pragma unroll
    for (int mi=0; mi<4; mi++)
      #pragma unroll
      for (int j=0;j<4;j++)
        red[wvid][mi*16 + (lane>>4)*4 + j] = psum[mi][j];
  }
  __syncthreads();

  // normalize and write P (bf16) into LDS
  #pragma unroll
  for (int mi=0; mi<4; mi++){
    #pragma unroll
    for (int j=0;j<4;j++){
      int r = mi*16 + (lane>>4)*4 + j;
      float tot = red[0][r] + red[1][r] + red[2][r] + red[3][r];
      float inv = 1.0f / tot;
      #pragma unroll
      for (int ni=0; ni<2; ni++){
        int col = wvid*32 + ni*16 + (lane&15);
        int ck = (col >> 3) ^ (r & 15);
        ps[r*128 + ck*8 + (col & 7)] = f2bf(pex[mi][ni][j] * inv);
      }
    }
  }
  __syncthreads();

  // out = P V ; wave wvid owns d-cols [wvid*16, wvid*16+16)
  f4v oacc[4];
  #pragma unroll
  for (int i=0;i<4;i++) oacc[i] = fzero;
  #pragma unroll
  for (int kk=0; kk<4; kk++){
    int d = wvid*16 + (lane&15);
    int cg = kk*4 + (lane>>4);
    s8v bfr = *(const s8v*)&vt[(d*16 + (cg ^ (d&15)))*8];
    #pragma unroll
    for (int mi=0; mi<4; mi++){
      int r = mi*16 + (lane&15);
      s8v afr = *(const s8v*)&ps[(r*16 + (cg ^ (r&15)))*8];
      oacc[mi] = __builtin_amdgcn_mfma_f32_16x16x32_bf16(afr, bfr, oacc[mi], 0,0,0);
    }
  }
  #pragma unroll
  for (int mi=0; mi<4; mi++)
    #pragma unroll
    for (int j=0;j<4;j++){
      int q = mi*16 + (lane>>4)*4 + j;
      Out[(size_t)wtok_idx(b,gh,gw,q)*512 + h*64 + wvid*16 + (lane&15)] = f2bf(oacc[mi][j]);
    }
}

// ---------------- launcher ----------------
extern "C" void kernel_launch(void* const* d_in, const int* in_sizes, int n_in,
                              void* d_out, int out_size, void* d_ws, size_t ws_size,
                              hipStream_t stream)
{
  const float* X   = (const float*)d_in[0];
  const float* F   = (const float*)d_in[1];
  const float* wq  = (const float*)d_in[2];
  const float* bq  = (const float*)d_in[3];
  const float* wk  = (const float*)d_in[4];
  const float* bk  = (const float*)d_in[5];
  const float* wv  = (const float*)d_in[6];
  const float* bv  = (const float*)d_in[7];
  const float* wo  = (const float*)d_in[8];
  const float* bo  = (const float*)d_in[9];
  const float* rww = (const float*)d_in[10];
  const float* rwb = (const float*)d_in[11];
  const float* ckw = (const float*)d_in[12];
  const float* ckb = (const float*)d_in[13];
  const float* cvw = (const float*)d_in[14];
  const float* cvb = (const float*)d_in[15];
  const float* qng = (const float*)d_in[16];
  const float* qnb = (const float*)d_in[17];
  const float* kng = (const float*)d_in[18];
  const float* knb = (const float*)d_in[19];
  const float* vng = (const float*)d_in[20];
  const float* vnb = (const float*)d_in[21];
  float* OutF = (float*)d_out;

  char* ws = (char*)d_ws;
  size_t off = 0;
  auto alloc = [&](size_t bytes){
    size_t o = off; off += (bytes + 255) & ~(size_t)255; return o;
  };
  u16*   W_RW = (u16*)  (ws + alloc((size_t)640*640*2));
  u16*   W_Q  = (u16*)  (ws + alloc((size_t)512*640*2));
  u16*   W_K  = (u16*)  (ws + alloc((size_t)512*640*2));
  u16*   W_V  = (u16*)  (ws + alloc((size_t)512*512*2));
  u16*   W_O  = (u16*)  (ws + alloc((size_t)512*512*2));
  float* B_Q  = (float*)(ws + alloc(512*4));
  float* B_K  = (float*)(ws + alloc(512*4));
  float* B_V  = (float*)(ws + alloc(512*4));
  u16*   QKB  = (u16*)  (ws + alloc((size_t)NTOK*640*2));   // qk bf16; reused as Qp
  u16*   QKRW = (u16*)  (ws + alloc((size_t)NTOK*640*2));   // reweighted; reused as attn_out
  u16*   U    = (u16*)  (ws + alloc((size_t)(NTOK+512)*640*2)); // normalized qk (+global k rows)
  u16*   UV   = (u16*)  (ws + alloc((size_t)(NTOK+512)*512*2)); // normalized x (+global v rows)
  u16*   KP   = (u16*)  (ws + alloc((size_t)(NTOK+512)*512*2));
  u16*   VP   = (u16*)  (ws + alloc((size_t)(NTOK+512)*512*2));
  (void)in_sizes; (void)n_in; (void)out_size; (void)ws_size;

  prep_weights<<<6208, 256, 0, stream>>>(rww, wq, wk, wv, wo, qng, kng, vng,
                                         W_RW, W_Q, W_K, W_V, W_O);
  prep_bias<<<6, 256, 0, stream>>>(wq, bq, qnb, wk, bk, knb, wv, bv, vnb, B_Q, B_K, B_V);
  build_qk<<<20480, 256, 0, stream>>>(X, F, QKB);

  // reweight: qk_rw = qk * sigmoid(qk @ rw_w^T + rw_b)
  gemm_kernel<1><<<1280, 256, 0, stream>>>(QKB, W_RW, rwb, QKRW, nullptr, X, F, 640, 640);

  ln_qk_kernel<<<8192, 256, 0, stream>>>(QKRW, U);
  ln_x_kernel<<<8192, 256, 0, stream>>>(X, UV);
  convk_ln_kernel<<<512, 640, 0, stream>>>(QKRW, ckw, ckb, U);
  convv_ln_kernel<<<512, 512, 0, stream>>>(X, cvw, cvb, UV);

  // projections (LN affine folded into weights/biases)
  gemm_kernel<0><<<1024, 256, 0, stream>>>(U,  W_Q, B_Q, QKB, nullptr, nullptr, nullptr, 512, 640); // Qp
  gemm_kernel<0><<<1040, 256, 0, stream>>>(U,  W_K, B_K, KP,  nullptr, nullptr, nullptr, 512, 640);
  gemm_kernel<0><<<1040, 256, 0, stream>>>(UV, W_V, B_V, VP,  nullptr, nullptr, nullptr, 512, 512);

  attn_kernel<<<4096, 256, 0, stream>>>(QKB, KP, VP, QKRW);

  // output projection -> f32 d_out
  gemm_kernel<2><<<1024, 256, 0, stream>>>(QKRW, W_O, bo, nullptr, OutF, nullptr, nullptr, 512, 512);
}

// Round 2
// 500.216 us; speedup vs baseline: 1.0556x; 1.0556x over previous
//
#include <hip/hip_runtime.h>

typedef unsigned short u16;
typedef __attribute__((ext_vector_type(8))) short s8v;
typedef __attribute__((ext_vector_type(4))) short s4v;
typedef __attribute__((ext_vector_type(4))) float f4v;

// H=W=64, WS=8, D=512, CF=128, INC=640, HEAD=8, DH=64
#define NTOK 32768
#define TTOK 33280   // 32768 window + 512 global tokens

__device__ __forceinline__ float bf2f(u16 u){
  union { unsigned int i; float f; } p; p.i = ((unsigned int)u) << 16; return p.f;
}
__device__ __forceinline__ u16 f2bf(float f){   // RNE
  union { float f; unsigned int i; } p; p.f = f;
  unsigned int r = p.i + 0x7FFFu + ((p.i >> 16) & 1u);
  return (u16)(r >> 16);
}
__device__ __forceinline__ int wtok_idx(int b, int gh, int gw, int n){
  return b*4096 + (gh*8 + (n>>3))*64 + gw*8 + (n&7);
}
// async global->LDS, 16B per lane; dest must be wave-uniform base (HW adds lane*16)
__device__ __forceinline__ void gload16(const u16* g, u16* l){
  __builtin_amdgcn_global_load_lds(
      (const __attribute__((address_space(1))) void*)g,
      (__attribute__((address_space(3))) void*)l, 16, 0, 0);
}

// ---------------- weight prep: bf16 convert + LN-gain fold ----------------
// W_QK is [1024][640]: rows 0..511 = wq*qng, rows 512..1023 = wk*kng
__global__ __launch_bounds__(256) void prep_weights(
    const float* __restrict__ rww, const float* __restrict__ wq,
    const float* __restrict__ wk,  const float* __restrict__ wv,
    const float* __restrict__ wo,  const float* __restrict__ qng,
    const float* __restrict__ kng, const float* __restrict__ vng,
    u16* __restrict__ orw, u16* __restrict__ oqk,
    u16* __restrict__ ov,  u16* __restrict__ oo)
{
  int i = blockIdx.x*256 + threadIdx.x;
  if (i < 409600){ orw[i] = f2bf(rww[i]); return; }
  i -= 409600;
  if (i < 327680){ oqk[i] = f2bf(wq[i] * qng[i % 640]); return; }
  i -= 327680;
  if (i < 327680){ oqk[327680 + i] = f2bf(wk[i] * kng[i % 640]); return; }
  i -= 327680;
  if (i < 262144){ ov[i] = f2bf(wv[i] * vng[i & 511]); return; }
  i -= 262144;
  oo[i] = f2bf(wo[i]);
}

// bias fold: b'_o = b_o + sum_i ln_b[i] * W[o,i]; B_QK[1024], B_V[512]
__global__ __launch_bounds__(256) void prep_bias(
    const float* __restrict__ wq, const float* __restrict__ bq, const float* __restrict__ qnb,
    const float* __restrict__ wk, const float* __restrict__ bk, const float* __restrict__ knb,
    const float* __restrict__ wv, const float* __restrict__ bv, const float* __restrict__ vnb,
    float* __restrict__ obqk, float* __restrict__ obv)
{
  int o = blockIdx.x*256 + threadIdx.x;  // 0..1535
  int which = o >> 9;
  int oo = o & 511;
  if (which == 0){
    float s = bq[oo];
    for (int i=0;i<640;i++) s += qnb[i]*wq[oo*640+i];
    obqk[oo] = s;
  } else if (which == 1){
    float s = bk[oo];
    for (int i=0;i<640;i++) s += knb[i]*wk[oo*640+i];
    obqk[512 + oo] = s;
  } else {
    float s = bv[oo];
    for (int i=0;i<512;i++) s += vnb[i]*wv[oo*512+i];
    obv[oo] = s;
  }
}

// ---------------- build qk = concat(x,f) as bf16 [32768][640] ----------------
__global__ __launch_bounds__(256) void build_qk(
    const float* __restrict__ X, const float* __restrict__ F, u16* __restrict__ qkb)
{
  int idx = blockIdx.x*256 + threadIdx.x;      // 32768*160 threads exactly
  int token = idx / 160;
  int c4 = (idx - token*160) * 4;
  f4v v;
  if (c4 < 512) v = *(const f4v*)(X + (size_t)token*512 + c4);
  else          v = *(const f4v*)(F + (size_t)token*128 + (c4 - 512));
  s4v o;
  #pragma unroll
  for (int j=0;j<4;j++) o[j] = (short)f2bf(v[j]);
  *(s4v*)(qkb + (size_t)token*640 + c4) = o;
}

// ---------------- GEMM: C[M,N] = A[M,K](bf16) * W[N,K](bf16)^T ----------------
// EPI 1: reweight: out0_bf16 = bf(A[row,col]) * sigmoid(acc + bias)   (N==K==640)
// EPI 2: outf_f32 = acc + bias                                        (N=512)
// EPI 3: VT transposed write: out0[col*TTOK + row] = acc + bias       (N=512)
// EPI 4: QK split: col<512 -> out0[row*512+col], else out1[row*512+col-512]
template<int EPI>
__global__ __launch_bounds__(256, 3) void gemm_kernel(
    const u16* __restrict__ A, const u16* __restrict__ B,
    const float* __restrict__ bias,
    u16* __restrict__ out0, u16* __restrict__ out1, float* __restrict__ outf,
    int N, int K)
{
  __shared__ u16 lA[128*64];
  __shared__ u16 lB[128*64];
  const int tid = threadIdx.x;
  const int lane = tid & 63;
  const int w = tid >> 6;
  const int wm = (w >> 1) * 64;
  const int wn = (w & 1) * 64;
  const int nb = N >> 7;
  const int m0 = (blockIdx.x / nb) << 7;
  const int n0 = (blockIdx.x % nb) << 7;
  const int wbase = tid & ~63;          // wave-uniform slot base

  const f4v fzero = {0.f, 0.f, 0.f, 0.f};
  f4v acc[4][4];
  #pragma unroll
  for (int i=0;i<4;i++)
    #pragma unroll
    for (int j=0;j<4;j++) acc[i][j] = fzero;

  for (int k0 = 0; k0 < K; k0 += 64){
    // async stage: linear LDS dest, source chunk pre-swizzled (cs = cc ^ row&7)
    #pragma unroll
    for (int it=0; it<4; it++){
      int s = it*256 + tid;
      int row = s >> 3, cc = s & 7, cs = cc ^ (row & 7);
      gload16(A + (size_t)(m0+row)*K + k0 + cs*8, &lA[(it*256 + wbase)*8]);
      gload16(B + (size_t)(n0+row)*K + k0 + cs*8, &lB[(it*256 + wbase)*8]);
    }
    __syncthreads();
    #pragma unroll
    for (int kk=0; kk<2; kk++){
      const int cg = kk*4 + (lane>>4);
      s8v bfr[4];
      #pragma unroll
      for (int ni=0; ni<4; ni++){
        int col = wn + ni*16 + (lane&15);
        bfr[ni] = *(const s8v*)&lB[(col*8 + (cg ^ (col&7)))*8];
      }
      #pragma unroll
      for (int mi=0; mi<4; mi++){
        int row = wm + mi*16 + (lane&15);
        s8v afr = *(const s8v*)&lA[(row*8 + (cg ^ (row&7)))*8];
        #pragma unroll
        for (int ni=0; ni<4; ni++)
          acc[mi][ni] = __builtin_amdgcn_mfma_f32_16x16x32_bf16(afr, bfr[ni], acc[mi][ni], 0, 0, 0);
      }
    }
    __syncthreads();
  }

  #pragma unroll
  for (int mi=0; mi<4; mi++){
    #pragma unroll
    for (int ni=0; ni<4; ni++){
      const int colg = n0 + wn + ni*16 + (lane&15);
      const float bb = bias[colg];
      if constexpr (EPI == 3){
        const int rowg0 = m0 + wm + mi*16 + (lane>>4)*4;
        s4v pk;
        #pragma unroll
        for (int j=0;j<4;j++) pk[j] = (short)f2bf(acc[mi][ni][j] + bb);
        *(s4v*)(out0 + (size_t)colg*TTOK + rowg0) = pk;
      } else {
        #pragma unroll
        for (int j=0;j<4;j++){
          const int rowg = m0 + wm + mi*16 + (lane>>4)*4 + j;
          float v = acc[mi][ni][j] + bb;
          if constexpr (EPI == 1){
            float sg = 1.f / (1.f + __expf(-v));
            float qv = bf2f(A[(size_t)rowg*640 + colg]);
            out0[(size_t)rowg*640 + colg] = f2bf(qv * sg);
          } else if constexpr (EPI == 2){
            outf[(size_t)rowg*512 + colg] = v;
          } else { // EPI 4
            if (colg < 512) out0[(size_t)rowg*512 + colg] = f2bf(v);
            else            out1[(size_t)rowg*512 + (colg-512)] = f2bf(v);
          }
        }
      }
    }
  }
}

// ---------------- LN (affine folded into weights); 16 lanes per token ----------
__global__ __launch_bounds__(256) void ln_qk_kernel(const u16* __restrict__ y, u16* __restrict__ u)
{
  int t = blockIdx.x*16 + (threadIdx.x >> 4);
  int l = threadIdx.x & 15;
  const u16* row = y + (size_t)t*640;
  s8v v[5];
  float s = 0.f, s2 = 0.f;
  #pragma unroll
  for (int p=0;p<5;p++){
    v[p] = *(const s8v*)(row + (p*16+l)*8);
    #pragma unroll
    for (int j=0;j<8;j++){ float x = bf2f((u16)v[p][j]); s += x; s2 += x*x; }
  }
  #pragma unroll
  for (int m=1;m<16;m<<=1){ s += __shfl_xor(s,m); s2 += __shfl_xor(s2,m); }
  float mean = s*(1.f/640.f);
  float var = s2*(1.f/640.f) - mean*mean;
  float rstd = rsqrtf(var + 1e-5f);
  u16* ur = u + (size_t)t*640;
  #pragma unroll
  for (int p=0;p<5;p++){
    s8v o;
    #pragma unroll
    for (int j=0;j<8;j++) o[j] = (short)f2bf((bf2f((u16)v[p][j])-mean)*rstd);
    *(s8v*)(ur + (p*16+l)*8) = o;
  }
}

__global__ __launch_bounds__(256) void ln_x_kernel(const float* __restrict__ X, u16* __restrict__ uv)
{
  int t = blockIdx.x*16 + (threadIdx.x >> 4);
  int l = threadIdx.x & 15;
  const float* row = X + (size_t)t*512;
  f4v v[8];
  float s = 0.f, s2 = 0.f;
  #pragma unroll
  for (int p=0;p<8;p++){
    v[p] = *(const f4v*)(row + (p*16+l)*4);
    #pragma unroll
    for (int j=0;j<4;j++){ float x = v[p][j]; s += x; s2 += x*x; }
  }
  #pragma unroll
  for (int m=1;m<16;m<<=1){ s += __shfl_xor(s,m); s2 += __shfl_xor(s2,m); }
  float mean = s*(1.f/512.f);
  float var = s2*(1.f/512.f) - mean*mean;
  float rstd = rsqrtf(var + 1e-5f);
  u16* ur = uv + (size_t)t*512;
  #pragma unroll
  for (int p=0;p<8;p++){
    s4v o;
    #pragma unroll
    for (int j=0;j<4;j++) o[j] = (short)f2bf((v[p][j]-mean)*rstd);
    *(s4v*)(ur + (p*16+l)*4) = o;
  }
}

// ---------------- depthwise 8x8 stride-8 conv + LN, global-token rows ----------
__global__ __launch_bounds__(640) void convk_ln_kernel(
    const u16* __restrict__ qkrw, const float* __restrict__ cw,
    const float* __restrict__ cb, u16* __restrict__ u)
{
  int bg = blockIdx.x;               // b*64 + gpos
  int b = bg >> 6, gpos = bg & 63;
  int gh = gpos >> 3, gw = gpos & 7;
  int ch = threadIdx.x;              // 0..639
  int base = b*4096 + gh*8*64 + gw*8;
  float acc = cb[ch];
  #pragma unroll
  for (int r=0;r<8;r++)
    #pragma unroll
    for (int c=0;c<8;c++)
      acc += bf2f(qkrw[(size_t)(base + r*64 + c)*640 + ch]) * cw[ch*64 + r*8 + c];
  float s = acc, s2 = acc*acc;
  #pragma unroll
  for (int m=1;m<64;m<<=1){ s += __shfl_xor(s,m); s2 += __shfl_xor(s2,m); }
  __shared__ float rs[10], rs2[10];
  int wid = threadIdx.x >> 6, lane = threadIdx.x & 63;
  if (lane == 0){ rs[wid] = s; rs2[wid] = s2; }
  __syncthreads();
  float ts = 0.f, ts2 = 0.f;
  #pragma unroll
  for (int i=0;i<10;i++){ ts += rs[i]; ts2 += rs2[i]; }
  float mean = ts*(1.f/640.f);
  float var = ts2*(1.f/640.f) - mean*mean;
  float rstd = rsqrtf(var + 1e-5f);
  u[(size_t)(NTOK + bg)*640 + ch] = f2bf((acc-mean)*rstd);
}

__global__ __launch_bounds__(512) void convv_ln_kernel(
    const float* __restrict__ X, const float* __restrict__ cw,
    const float* __restrict__ cb, u16* __restrict__ uv)
{
  int bg = blockIdx.x;
  int b = bg >> 6, gpos = bg & 63;
  int gh = gpos >> 3, gw = gpos & 7;
  int ch = threadIdx.x;              // 0..511
  int base = b*4096 + gh*8*64 + gw*8;
  float acc = cb[ch];
  #pragma unroll
  for (int r=0;r<8;r++)
    #pragma unroll
    for (int c=0;c<8;c++)
      acc += X[(size_t)(base + r*64 + c)*512 + ch] * cw[ch*64 + r*8 + c];
  float s = acc, s2 = acc*acc;
  #pragma unroll
  for (int m=1;m<64;m<<=1){ s += __shfl_xor(s,m); s2 += __shfl_xor(s2,m); }
  __shared__ float rs[8], rs2[8];
  int wid = threadIdx.x >> 6, lane = threadIdx.x & 63;
  if (lane == 0){ rs[wid] = s; rs2[wid] = s2; }
  __syncthreads();
  float ts = 0.f, ts2 = 0.f;
  #pragma unroll
  for (int i=0;i<8;i++){ ts += rs[i]; ts2 += rs2[i]; }
  float mean = ts*(1.f/512.f);
  float var = ts2*(1.f/512.f) - mean*mean;
  float rstd = rsqrtf(var + 1e-5f);
  uv[(size_t)(NTOK + bg)*512 + ch] = f2bf((acc-mean)*rstd);
}

// ---------------- attention v2: direct-global fragments, P-only LDS ----------
// Per (b,g,h) block: Q 64x64 (A-frags from Qp rows), K 128x64 (B-frags from Kp
// rows), V^T (B-frags from VT[h*64+d][tok]). Softmax f32, P via swizzled LDS.
__global__ __launch_bounds__(256, 3) void attn_kernel(
    const u16* __restrict__ Qp, const u16* __restrict__ Kp,
    const u16* __restrict__ VT, u16* __restrict__ Out)
{
  int blk = blockIdx.x;                 // b*512 + g*8 + h
  int h = blk & 7, g = (blk >> 3) & 63, b = blk >> 9;
  int gh = g >> 3, gw = g & 7;
  int tid = threadIdx.x, lane = tid & 63, wvid = tid >> 6;
  int l15 = lane & 15, lg = lane >> 4;

  __shared__ u16 ps[64*128];   // P: [q][ktok], 16 chunks/row, swz ^(q&15)
  __shared__ float red[4][64];

  // ---- fragment loads (all independent; issued up front) ----
  s8v qf[4][2], kf[2][2], vf[4];
  #pragma unroll
  for (int mi=0; mi<4; mi++){
    const u16* qrow = Qp + (size_t)wtok_idx(b,gh,gw, mi*16 + l15)*512 + h*64;
    #pragma unroll
    for (int kk=0; kk<2; kk++)
      qf[mi][kk] = *(const s8v*)(qrow + (kk*4+lg)*8);
  }
  #pragma unroll
  for (int ni=0; ni<2; ni++){
    int kt = wvid*32 + ni*16 + l15;
    int tok = (kt < 64) ? wtok_idx(b,gh,gw,kt) : (NTOK + b*64 + (kt-64));
    const u16* krow = Kp + (size_t)tok*512 + h*64;
    #pragma unroll
    for (int kk=0; kk<2; kk++)
      kf[ni][kk] = *(const s8v*)(krow + (kk*4+lg)*8);
  }
  {
    int d = wvid*16 + l15;
    const u16* vrow = VT + (size_t)(h*64 + d)*TTOK;
    #pragma unroll
    for (int c4=0; c4<4; c4++){
      int kt0 = (c4*4+lg)*8;
      int tok0 = (kt0 < 64) ? wtok_idx(b,gh,gw,kt0) : (NTOK + b*64 + (kt0-64));
      vf[c4] = *(const s8v*)(vrow + tok0);   // 8 consecutive tokens
    }
  }

  // ---- S = Q K^T ; wave owns ktok cols [wvid*32, +32) ----
  const f4v fzero = {0.f,0.f,0.f,0.f};
  f4v sacc[4][2];
  #pragma unroll
  for (int i=0;i<4;i++){ sacc[i][0]=fzero; sacc[i][1]=fzero; }
  #pragma unroll
  for (int kk=0; kk<2; kk++)
    #pragma unroll
    for (int mi=0; mi<4; mi++)
      #pragma unroll
      for (int ni=0; ni<2; ni++)
        sacc[mi][ni] = __builtin_amdgcn_mfma_f32_16x16x32_bf16(qf[mi][kk], kf[ni][kk], sacc[mi][ni], 0,0,0);

  // ---- exp(S/8), per-row partial sums over this wave's 32 cols ----
  float psum[4][4];
  #pragma unroll
  for (int mi=0; mi<4; mi++){
    #pragma unroll
    for (int j=0;j<4;j++){
      float e0 = __expf(sacc[mi][0][j] * 0.125f);
      float e1 = __expf(sacc[mi][1][j] * 0.125f);
      sacc[mi][0][j] = e0; sacc[mi][1][j] = e1;
      float t0 = e0 + e1;
      #pragma unroll
      for (int m=1;m<16;m<<=1) t0 += __shfl_xor(t0, m);
      psum[mi][j] = t0;
    }
  }
  if (l15 == 0){
    #pragma unroll
    for (int mi=0; mi<4; mi++)
      #pragma unroll
      for (int j=0;j<4;j++)
        red[wvid][mi*16 + lg*4 + j] = psum[mi][j];
  }
  __syncthreads();

  // ---- normalize, write P to LDS ----
  #pragma unroll
  for (int mi=0; mi<4; mi++){
    #pragma unroll
    for (int j=0;j<4;j++){
      int r = mi*16 + lg*4 + j;
      float inv = 1.0f / (red[0][r] + red[1][r] + red[2][r] + red[3][r]);
      #pragma unroll
      for (int ni=0; ni<2; ni++){
        int col = wvid*32 + ni*16 + l15;
        int ck = (col >> 3) ^ (r & 15);
        ps[r*128 + ck*8 + (col & 7)] = f2bf(sacc[mi][ni][j] * inv);
      }
    }
  }
  __syncthreads();

  // ---- O = P V ; wave owns d-cols [wvid*16, +16) ----
  f4v oacc[4];
  #pragma unroll
  for (int i=0;i<4;i++) oacc[i] = fzero;
  #pragma unroll
  for (int c4=0; c4<4; c4++){
    int cg = c4*4 + lg;
    #pragma unroll
    for (int mi=0; mi<4; mi++){
      s8v afr = *(const s8v*)&ps[((mi*16 + l15)*16 + (cg ^ l15))*8];
      oacc[mi] = __builtin_amdgcn_mfma_f32_16x16x32_bf16(afr, vf[c4], oacc[mi], 0,0,0);
    }
  }
  #pragma unroll
  for (int mi=0; mi<4; mi++)
    #pragma unroll
    for (int j=0;j<4;j++){
      int q = mi*16 + lg*4 + j;
      Out[(size_t)wtok_idx(b,gh,gw,q)*512 + h*64 + wvid*16 + l15] = f2bf(oacc[mi][j]);
    }
}

// ---------------- launcher ----------------
extern "C" void kernel_launch(void* const* d_in, const int* in_sizes, int n_in,
                              void* d_out, int out_size, void* d_ws, size_t ws_size,
                              hipStream_t stream)
{
  const float* X   = (const float*)d_in[0];
  const float* F   = (const float*)d_in[1];
  const float* wq  = (const float*)d_in[2];
  const float* bq  = (const float*)d_in[3];
  const float* wk  = (const float*)d_in[4];
  const float* bk  = (const float*)d_in[5];
  const float* wv  = (const float*)d_in[6];
  const float* bv  = (const float*)d_in[7];
  const float* wo  = (const float*)d_in[8];
  const float* bo  = (const float*)d_in[9];
  const float* rww = (const float*)d_in[10];
  const float* rwb = (const float*)d_in[11];
  const float* ckw = (const float*)d_in[12];
  const float* ckb = (const float*)d_in[13];
  const float* cvw = (const float*)d_in[14];
  const float* cvb = (const float*)d_in[15];
  const float* qng = (const float*)d_in[16];
  const float* qnb = (const float*)d_in[17];
  const float* kng = (const float*)d_in[18];
  const float* knb = (const float*)d_in[19];
  const float* vng = (const float*)d_in[20];
  const float* vnb = (const float*)d_in[21];
  float* OutF = (float*)d_out;

  char* ws = (char*)d_ws;
  size_t off = 0;
  auto alloc = [&](size_t bytes){
    size_t o = off; off += (bytes + 255) & ~(size_t)255; return o;
  };
  u16*   W_RW = (u16*)  (ws + alloc((size_t)640*640*2));
  u16*   W_QK = (u16*)  (ws + alloc((size_t)1024*640*2));
  u16*   W_V  = (u16*)  (ws + alloc((size_t)512*512*2));
  u16*   W_O  = (u16*)  (ws + alloc((size_t)512*512*2));
  float* B_QK = (float*)(ws + alloc(1024*4));
  float* B_V  = (float*)(ws + alloc(512*4));
  u16*   QKB  = (u16*)  (ws + alloc((size_t)NTOK*640*2));   // qk bf16; reused as Qp [TTOK][512]
  u16*   QKRW = (u16*)  (ws + alloc((size_t)NTOK*640*2));   // reweighted; reused as attn_out
  u16*   U    = (u16*)  (ws + alloc((size_t)TTOK*640*2));   // normalized qk (+global k rows)
  u16*   UV   = (u16*)  (ws + alloc((size_t)TTOK*512*2));   // normalized x (+global v rows)
  u16*   KP   = (u16*)  (ws + alloc((size_t)TTOK*512*2));
  u16*   VT   = (u16*)  (ws + alloc((size_t)512*TTOK*2));   // V^T: [h*64+d][tok]
  (void)in_sizes; (void)n_in; (void)out_size; (void)ws_size;

  prep_weights<<<6208, 256, 0, stream>>>(rww, wq, wk, wv, wo, qng, kng, vng,
                                         W_RW, W_QK, W_V, W_O);
  prep_bias<<<6, 256, 0, stream>>>(wq, bq, qnb, wk, bk, knb, wv, bv, vnb, B_QK, B_V);
  build_qk<<<20480, 256, 0, stream>>>(X, F, QKB);

  // reweight: qk_rw = qk * sigmoid(qk @ rw_w^T + rw_b)
  gemm_kernel<1><<<1280, 256, 0, stream>>>(QKB, W_RW, rwb, QKRW, nullptr, nullptr, 640, 640);

  ln_qk_kernel<<<2048, 256, 0, stream>>>(QKRW, U);
  ln_x_kernel<<<2048, 256, 0, stream>>>(X, UV);
  convk_ln_kernel<<<512, 640, 0, stream>>>(QKRW, ckw, ckb, U);
  convv_ln_kernel<<<512, 512, 0, stream>>>(X, cvw, cvb, UV);

  // merged Q+K projection (N=1024), V projection with transposed epilogue
  gemm_kernel<4><<<2080, 256, 0, stream>>>(U,  W_QK, B_QK, QKB, KP, nullptr, 1024, 640);
  gemm_kernel<3><<<1040, 256, 0, stream>>>(UV, W_V,  B_V,  VT,  nullptr, nullptr, 512, 512);

  attn_kernel<<<4096, 256, 0, stream>>>(QKB, KP, VT, QKRW);

  // output projection -> f32 d_out
  gemm_kernel<2><<<1024, 256, 0, stream>>>(QKRW, W_O, bo, nullptr, nullptr, OutF, 512, 512);
}

// Round 3
// 456.423 us; speedup vs baseline: 1.1569x; 1.0959x over previous
//
#include <hip/hip_runtime.h>

typedef unsigned short u16;
typedef __attribute__((ext_vector_type(8))) short s8v;
typedef __attribute__((ext_vector_type(4))) short s4v;
typedef __attribute__((ext_vector_type(4))) float f4v;

// H=W=64, WS=8, D=512, CF=128, INC=640, HEAD=8, DH=64
#define NTOK 32768
#define TTOK 33280   // 32768 window + 512 global tokens

__device__ __forceinline__ float bf2f(u16 u){
  union { unsigned int i; float f; } p; p.i = ((unsigned int)u) << 16; return p.f;
}
__device__ __forceinline__ u16 f2bf(float f){   // RNE
  union { float f; unsigned int i; } p; p.f = f;
  unsigned int r = p.i + 0x7FFFu + ((p.i >> 16) & 1u);
  return (u16)(r >> 16);
}
__device__ __forceinline__ int wtok_idx(int b, int gh, int gw, int n){
  return b*4096 + (gh*8 + (n>>3))*64 + gw*8 + (n&7);
}
// async global->LDS, 16B per lane; dest is wave-uniform base (HW adds lane*16)
__device__ __forceinline__ void gload16(const u16* g, u16* l){
  __builtin_amdgcn_global_load_lds(
      (const __attribute__((address_space(1))) void*)g,
      (__attribute__((address_space(3))) void*)l, 16, 0, 0);
}

// ---------------- weight prep: bf16 convert + LN-gain fold ----------------
// W_QK is [1024][640]: rows 0..511 = wq*qng, rows 512..1023 = wk*kng
__global__ __launch_bounds__(256) void prep_weights(
    const float* __restrict__ rww, const float* __restrict__ wq,
    const float* __restrict__ wk,  const float* __restrict__ wv,
    const float* __restrict__ wo,  const float* __restrict__ qng,
    const float* __restrict__ kng, const float* __restrict__ vng,
    u16* __restrict__ orw, u16* __restrict__ oqk,
    u16* __restrict__ ov,  u16* __restrict__ oo)
{
  int i = blockIdx.x*256 + threadIdx.x;
  if (i < 409600){ orw[i] = f2bf(rww[i]); return; }
  i -= 409600;
  if (i < 327680){ oqk[i] = f2bf(wq[i] * qng[i % 640]); return; }
  i -= 327680;
  if (i < 327680){ oqk[327680 + i] = f2bf(wk[i] * kng[i % 640]); return; }
  i -= 327680;
  if (i < 262144){ ov[i] = f2bf(wv[i] * vng[i & 511]); return; }
  i -= 262144;
  oo[i] = f2bf(wo[i]);
}

// bias fold b'_o = b_o + sum_i ln_b[i]*W'[o,i], and wsum_o = sum_i W'[o,i]
// (W' = LN-gain-folded weights). B_QK/WS_QK [1024], B_V/WS_V [512].
__global__ __launch_bounds__(256) void prep_bias(
    const float* __restrict__ wq, const float* __restrict__ bq, const float* __restrict__ qnb,
    const float* __restrict__ qng,
    const float* __restrict__ wk, const float* __restrict__ bk, const float* __restrict__ knb,
    const float* __restrict__ kng,
    const float* __restrict__ wv, const float* __restrict__ bv, const float* __restrict__ vnb,
    const float* __restrict__ vng,
    float* __restrict__ obqk, float* __restrict__ obv,
    float* __restrict__ owsqk, float* __restrict__ owsv)
{
  int o = blockIdx.x*256 + threadIdx.x;  // 0..1535
  int which = o >> 9;
  int oo = o & 511;
  if (which == 0){
    float s = bq[oo], ws = 0.f;
    for (int i=0;i<640;i++){ float w = wq[oo*640+i]*qng[i]; s += qnb[i]*wq[oo*640+i]; ws += w; }
    obqk[oo] = s; owsqk[oo] = ws;
  } else if (which == 1){
    float s = bk[oo], ws = 0.f;
    for (int i=0;i<640;i++){ float w = wk[oo*640+i]*kng[i]; s += knb[i]*wk[oo*640+i]; ws += w; }
    obqk[512 + oo] = s; owsqk[512 + oo] = ws;
  } else {
    float s = bv[oo], ws = 0.f;
    for (int i=0;i<512;i++){ float w = wv[oo*512+i]*vng[i]; s += vnb[i]*wv[oo*512+i]; ws += w; }
    obv[oo] = s; owsv[oo] = ws;
  }
}

// ---------------- build qk = concat(x,f) as bf16 [32768][640] ----------------
__global__ __launch_bounds__(256) void build_qk(
    const float* __restrict__ X, const float* __restrict__ F, u16* __restrict__ qkb)
{
  int idx = blockIdx.x*256 + threadIdx.x;      // 32768*160 threads exactly
  int token = idx / 160;
  int c4 = (idx - token*160) * 4;
  f4v v;
  if (c4 < 512) v = *(const f4v*)(X + (size_t)token*512 + c4);
  else          v = *(const f4v*)(F + (size_t)token*128 + (c4 - 512));
  s4v o;
  #pragma unroll
  for (int j=0;j<4;j++) o[j] = (short)f2bf(v[j]);
  *(s4v*)(qkb + (size_t)token*640 + c4) = o;
}

// ---------------- row stats: mean/rstd over bf16 rows ----------------
// NC = channels (640 or 512), stride = row stride in elements
template<int NC>
__global__ __launch_bounds__(256) void row_stats(
    const u16* __restrict__ A, int stride, float* __restrict__ om, float* __restrict__ os)
{
  int t = blockIdx.x*16 + (threadIdx.x >> 4);
  int l = threadIdx.x & 15;
  const u16* row = A + (size_t)t*stride;
  float s = 0.f, s2 = 0.f;
  #pragma unroll
  for (int p=0; p<NC/128; p++){
    s8v v = *(const s8v*)(row + (p*16+l)*8);
    #pragma unroll
    for (int j=0;j<8;j++){ float x = bf2f((u16)v[j]); s += x; s2 += x*x; }
  }
  #pragma unroll
  for (int m=1;m<16;m<<=1){ s += __shfl_xor(s,m); s2 += __shfl_xor(s2,m); }
  if (l == 0){
    float mean = s*(1.f/NC);
    float var = s2*(1.f/NC) - mean*mean;
    om[t] = mean;
    os[t] = rsqrtf(var + 1e-5f);
  }
}

// ---------------- GEMM: C[M,N] = A[M,K](bf16) * W[N,K](bf16)^T ----------------
// A rows >= NTOK come from A2 (conv tokens, pre-normalized, stats=(0,1)).
// STATS: epilogue applies v = s*acc - s*m*wsum[col] + bias[col]  (LN fold)
// EPI 1: reweight: out0 = bf(A[row,col]) * sigmoid(acc + bias)   (N==K==640)
// EPI 2: outf_f32 = acc + bias                                   (out proj)
// EPI 3: VT transposed: out0[col*TTOK + row] (with stats)
// EPI 4: QK split: col<512 -> out0 (Q), else out1 (K)  (with stats)
template<int EPI, bool STATS>
__global__ __launch_bounds__(256, 3) void gemm_kernel(
    const u16* __restrict__ A, int strideA,
    const u16* __restrict__ A2, int strideA2,
    const u16* __restrict__ B, const float* __restrict__ bias,
    const float* __restrict__ wsum,
    const float* __restrict__ rmean, const float* __restrict__ rrstd,
    u16* __restrict__ out0, u16* __restrict__ out1, float* __restrict__ outf,
    int N, int K)
{
  __shared__ u16 lA[128*64];
  __shared__ u16 lB[128*64];
  const int tid = threadIdx.x;
  const int lane = tid & 63;
  const int w = tid >> 6;
  const int wm = (w >> 1) * 64;
  const int wn = (w & 1) * 64;
  const int nb = N >> 7;
  // bijective XCD swizzle (grid %8 == 0): XCD x owns a contiguous tile range
  const int nwg = (int)gridDim.x;
  const int wg = ((int)blockIdx.x & 7) * (nwg >> 3) + ((int)blockIdx.x >> 3);
  const int m0 = (wg / nb) << 7;
  const int n0 = (wg % nb) << 7;
  const int wbase = tid & ~63;          // wave-uniform slot base

  const f4v fzero = {0.f, 0.f, 0.f, 0.f};
  f4v acc[4][4];
  #pragma unroll
  for (int i=0;i<4;i++)
    #pragma unroll
    for (int j=0;j<4;j++) acc[i][j] = fzero;

  for (int k0 = 0; k0 < K; k0 += 64){
    // async stage: linear LDS dest, source chunk pre-swizzled (cs = cc ^ row&7)
    #pragma unroll
    for (int it=0; it<4; it++){
      int s = it*256 + tid;
      int row = s >> 3, cc = s & 7, cs = cc ^ (row & 7);
      int rr = m0 + row;
      const u16* aptr = (rr < NTOK)
          ? A  + (size_t)rr*strideA  + k0 + cs*8
          : A2 + (size_t)(rr - NTOK)*strideA2 + k0 + cs*8;
      gload16(aptr, &lA[(it*256 + wbase)*8]);
      gload16(B + (size_t)(n0+row)*K + k0 + cs*8, &lB[(it*256 + wbase)*8]);
    }
    __syncthreads();
    #pragma unroll
    for (int kk=0; kk<2; kk++){
      const int cg = kk*4 + (lane>>4);
      s8v bfr[4];
      #pragma unroll
      for (int ni=0; ni<4; ni++){
        int col = wn + ni*16 + (lane&15);
        bfr[ni] = *(const s8v*)&lB[(col*8 + (cg ^ (col&7)))*8];
      }
      #pragma unroll
      for (int mi=0; mi<4; mi++){
        int row = wm + mi*16 + (lane&15);
        s8v afr = *(const s8v*)&lA[(row*8 + (cg ^ (row&7)))*8];
        #pragma unroll
        for (int ni=0; ni<4; ni++)
          acc[mi][ni] = __builtin_amdgcn_mfma_f32_16x16x32_bf16(afr, bfr[ni], acc[mi][ni], 0, 0, 0);
      }
    }
    __syncthreads();
  }

  #pragma unroll
  for (int mi=0; mi<4; mi++){
    // per-row LN stats for this lane's 4 rows
    float rs[4], rm[4];
    if constexpr (STATS){
      #pragma unroll
      for (int j=0;j<4;j++){
        int rowg = m0 + wm + mi*16 + (lane>>4)*4 + j;
        rs[j] = rrstd[rowg]; rm[j] = rmean[rowg];
      }
    }
    #pragma unroll
    for (int ni=0; ni<4; ni++){
      const int colg = n0 + wn + ni*16 + (lane&15);
      const float bb = bias[colg];
      const float wsc = STATS ? wsum[colg] : 0.f;
      if constexpr (EPI == 3){
        const int rowg0 = m0 + wm + mi*16 + (lane>>4)*4;
        s4v pk;
        #pragma unroll
        for (int j=0;j<4;j++){
          float v = STATS ? (rs[j]*acc[mi][ni][j] - rs[j]*rm[j]*wsc + bb)
                          : (acc[mi][ni][j] + bb);
          pk[j] = (short)f2bf(v);
        }
        *(s4v*)(out0 + (size_t)colg*TTOK + rowg0) = pk;
      } else {
        #pragma unroll
        for (int j=0;j<4;j++){
          const int rowg = m0 + wm + mi*16 + (lane>>4)*4 + j;
          float v = STATS ? (rs[j]*acc[mi][ni][j] - rs[j]*rm[j]*wsc + bb)
                          : (acc[mi][ni][j] + bb);
          if constexpr (EPI == 1){
            float sg = 1.f / (1.f + __expf(-v));
            float qv = bf2f(A[(size_t)rowg*640 + colg]);
            out0[(size_t)rowg*640 + colg] = f2bf(qv * sg);
          } else if constexpr (EPI == 2){
            outf[(size_t)rowg*512 + colg] = v;
          } else { // EPI 4
            if (colg < 512) out0[(size_t)rowg*512 + colg] = f2bf(v);
            else            out1[(size_t)rowg*512 + (colg-512)] = f2bf(v);
          }
        }
      }
    }
  }
}

// ---------------- depthwise 8x8 stride-8 conv + LN, pre-normalized rows ------
__global__ __launch_bounds__(640) void convk_ln_kernel(
    const u16* __restrict__ qkrw, const float* __restrict__ cw,
    const float* __restrict__ cb, u16* __restrict__ qkc,
    float* __restrict__ om, float* __restrict__ os)
{
  int bg = blockIdx.x;               // b*64 + gpos
  int b = bg >> 6, gpos = bg & 63;
  int gh = gpos >> 3, gw = gpos & 7;
  int ch = threadIdx.x;              // 0..639
  int base = b*4096 + gh*8*64 + gw*8;
  float acc = cb[ch];
  #pragma unroll
  for (int r=0;r<8;r++)
    #pragma unroll
    for (int c=0;c<8;c++)
      acc += bf2f(qkrw[(size_t)(base + r*64 + c)*640 + ch]) * cw[ch*64 + r*8 + c];
  float s = acc, s2 = acc*acc;
  #pragma unroll
  for (int m=1;m<64;m<<=1){ s += __shfl_xor(s,m); s2 += __shfl_xor(s2,m); }
  __shared__ float rs[10], rs2[10];
  int wid = threadIdx.x >> 6, lane = threadIdx.x & 63;
  if (lane == 0){ rs[wid] = s; rs2[wid] = s2; }
  __syncthreads();
  float ts = 0.f, ts2 = 0.f;
  #pragma unroll
  for (int i=0;i<10;i++){ ts += rs[i]; ts2 += rs2[i]; }
  float mean = ts*(1.f/640.f);
  float var = ts2*(1.f/640.f) - mean*mean;
  float rstd = rsqrtf(var + 1e-5f);
  qkc[(size_t)bg*640 + ch] = f2bf((acc-mean)*rstd);
  if (ch == 0){ om[NTOK + bg] = 0.f; os[NTOK + bg] = 1.f; }
}

__global__ __launch_bounds__(512) void convv_ln_kernel(
    const float* __restrict__ X, const float* __restrict__ cw,
    const float* __restrict__ cb, u16* __restrict__ xc,
    float* __restrict__ om, float* __restrict__ os)
{
  int bg = blockIdx.x;
  int b = bg >> 6, gpos = bg & 63;
  int gh = gpos >> 3, gw = gpos & 7;
  int ch = threadIdx.x;              // 0..511
  int base = b*4096 + gh*8*64 + gw*8;
  float acc = cb[ch];
  #pragma unroll
  for (int r=0;r<8;r++)
    #pragma unroll
    for (int c=0;c<8;c++)
      acc += X[(size_t)(base + r*64 + c)*512 + ch] * cw[ch*64 + r*8 + c];
  float s = acc, s2 = acc*acc;
  #pragma unroll
  for (int m=1;m<64;m<<=1){ s += __shfl_xor(s,m); s2 += __shfl_xor(s2,m); }
  __shared__ float rs[8], rs2[8];
  int wid = threadIdx.x >> 6, lane = threadIdx.x & 63;
  if (lane == 0){ rs[wid] = s; rs2[wid] = s2; }
  __syncthreads();
  float ts = 0.f, ts2 = 0.f;
  #pragma unroll
  for (int i=0;i<8;i++){ ts += rs[i]; ts2 += rs2[i]; }
  float mean = ts*(1.f/512.f);
  float var = ts2*(1.f/512.f) - mean*mean;
  float rstd = rsqrtf(var + 1e-5f);
  xc[(size_t)bg*512 + ch] = f2bf((acc-mean)*rstd);
  if (ch == 0){ om[NTOK + bg] = 0.f; os[NTOK + bg] = 1.f; }
}

// ---------------- attention: direct-global fragments, P-only LDS ----------
__global__ __launch_bounds__(256, 3) void attn_kernel(
    const u16* __restrict__ Qp, const u16* __restrict__ Kp,
    const u16* __restrict__ VT, u16* __restrict__ Out)
{
  int blk = blockIdx.x;                 // b*512 + g*8 + h
  int h = blk & 7, g = (blk >> 3) & 63, b = blk >> 9;
  int gh = g >> 3, gw = g & 7;
  int tid = threadIdx.x, lane = tid & 63, wvid = tid >> 6;
  int l15 = lane & 15, lg = lane >> 4;

  __shared__ u16 ps[64*128];   // P: [q][ktok], 16 chunks/row, swz ^(q&15)
  __shared__ float red[4][64];

  // ---- fragment loads (all independent; issued up front) ----
  s8v qf[4][2], kf[2][2], vf[4];
  #pragma unroll
  for (int mi=0; mi<4; mi++){
    const u16* qrow = Qp + (size_t)wtok_idx(b,gh,gw, mi*16 + l15)*512 + h*64;
    #pragma unroll
    for (int kk=0; kk<2; kk++)
      qf[mi][kk] = *(const s8v*)(qrow + (kk*4+lg)*8);
  }
  #pragma unroll
  for (int ni=0; ni<2; ni++){
    int kt = wvid*32 + ni*16 + l15;
    int tok = (kt < 64) ? wtok_idx(b,gh,gw,kt) : (NTOK + b*64 + (kt-64));
    const u16* krow = Kp + (size_t)tok*512 + h*64;
    #pragma unroll
    for (int kk=0; kk<2; kk++)
      kf[ni][kk] = *(const s8v*)(krow + (kk*4+lg)*8);
  }
  {
    int d = wvid*16 + l15;
    const u16* vrow = VT + (size_t)(h*64 + d)*TTOK;
    #pragma unroll
    for (int c4=0; c4<4; c4++){
      int kt0 = (c4*4+lg)*8;
      int tok0 = (kt0 < 64) ? wtok_idx(b,gh,gw,kt0) : (NTOK + b*64 + (kt0-64));
      vf[c4] = *(const s8v*)(vrow + tok0);   // 8 consecutive tokens
    }
  }

  // ---- S = Q K^T ; wave owns ktok cols [wvid*32, +32) ----
  const f4v fzero = {0.f,0.f,0.f,0.f};
  f4v sacc[4][2];
  #pragma unroll
  for (int i=0;i<4;i++){ sacc[i][0]=fzero; sacc[i][1]=fzero; }
  #pragma unroll
  for (int kk=0; kk<2; kk++)
    #pragma unroll
    for (int mi=0; mi<4; mi++)
      #pragma unroll
      for (int ni=0; ni<2; ni++)
        sacc[mi][ni] = __builtin_amdgcn_mfma_f32_16x16x32_bf16(qf[mi][kk], kf[ni][kk], sacc[mi][ni], 0,0,0);

  // ---- exp(S/8), per-row partial sums over this wave's 32 cols ----
  float psum[4][4];
  #pragma unroll
  for (int mi=0; mi<4; mi++){
    #pragma unroll
    for (int j=0;j<4;j++){
      float e0 = __expf(sacc[mi][0][j] * 0.125f);
      float e1 = __expf(sacc[mi][1][j] * 0.125f);
      sacc[mi][0][j] = e0; sacc[mi][1][j] = e1;
      float t0 = e0 + e1;
      #pragma unroll
      for (int m=1;m<16;m<<=1) t0 += __shfl_xor(t0, m);
      psum[mi][j] = t0;
    }
  }
  if (l15 == 0){
    #pragma unroll
    for (int mi=0; mi<4; mi++)
      #pragma unroll
      for (int j=0;j<4;j++)
        red[wvid][mi*16 + lg*4 + j] = psum[mi][j];
  }
  __syncthreads();

  // ---- normalize, write P to LDS ----
  #pragma unroll
  for (int mi=0; mi<4; mi++){
    #pragma unroll
    for (int j=0;j<4;j++){
      int r = mi*16 + lg*4 + j;
      float inv = 1.0f / (red[0][r] + red[1][r] + red[2][r] + red[3][r]);
      #pragma unroll
      for (int ni=0; ni<2; ni++){
        int col = wvid*32 + ni*16 + l15;
        int ck = (col >> 3) ^ (r & 15);
        ps[r*128 + ck*8 + (col & 7)] = f2bf(sacc[mi][ni][j] * inv);
      }
    }
  }
  __syncthreads();

  // ---- O = P V ; wave owns d-cols [wvid*16, +16) ----
  f4v oacc[4];
  #pragma unroll
  for (int i=0;i<4;i++) oacc[i] = fzero;
  #pragma unroll
  for (int c4=0; c4<4; c4++){
    int cg = c4*4 + lg;
    #pragma unroll
    for (int mi=0; mi<4; mi++){
      s8v afr = *(const s8v*)&ps[((mi*16 + l15)*16 + (cg ^ l15))*8];
      oacc[mi] = __builtin_amdgcn_mfma_f32_16x16x32_bf16(afr, vf[c4], oacc[mi], 0,0,0);
    }
  }
  #pragma unroll
  for (int mi=0; mi<4; mi++)
    #pragma unroll
    for (int j=0;j<4;j++){
      int q = mi*16 + lg*4 + j;
      Out[(size_t)wtok_idx(b,gh,gw,q)*512 + h*64 + wvid*16 + l15] = f2bf(oacc[mi][j]);
    }
}

// ---------------- launcher ----------------
extern "C" void kernel_launch(void* const* d_in, const int* in_sizes, int n_in,
                              void* d_out, int out_size, void* d_ws, size_t ws_size,
                              hipStream_t stream)
{
  const float* X   = (const float*)d_in[0];
  const float* F   = (const float*)d_in[1];
  const float* wq  = (const float*)d_in[2];
  const float* bq  = (const float*)d_in[3];
  const float* wk  = (const float*)d_in[4];
  const float* bk  = (const float*)d_in[5];
  const float* wv  = (const float*)d_in[6];
  const float* bv  = (const float*)d_in[7];
  const float* wo  = (const float*)d_in[8];
  const float* bo  = (const float*)d_in[9];
  const float* rww = (const float*)d_in[10];
  const float* rwb = (const float*)d_in[11];
  const float* ckw = (const float*)d_in[12];
  const float* ckb = (const float*)d_in[13];
  const float* cvw = (const float*)d_in[14];
  const float* cvb = (const float*)d_in[15];
  const float* qng = (const float*)d_in[16];
  const float* qnb = (const float*)d_in[17];
  const float* kng = (const float*)d_in[18];
  const float* knb = (const float*)d_in[19];
  const float* vng = (const float*)d_in[20];
  const float* vnb = (const float*)d_in[21];
  float* OutF = (float*)d_out;

  char* ws = (char*)d_ws;
  size_t off = 0;
  auto alloc = [&](size_t bytes){
    size_t o = off; off += (bytes + 255) & ~(size_t)255; return o;
  };
  u16*   W_RW = (u16*)  (ws + alloc((size_t)640*640*2));
  u16*   W_QK = (u16*)  (ws + alloc((size_t)1024*640*2));
  u16*   W_V  = (u16*)  (ws + alloc((size_t)512*512*2));
  u16*   W_O  = (u16*)  (ws + alloc((size_t)512*512*2));
  float* B_QK = (float*)(ws + alloc(1024*4));
  float* B_V  = (float*)(ws + alloc(512*4));
  float* WS_QK= (float*)(ws + alloc(1024*4));
  float* WS_V = (float*)(ws + alloc(512*4));
  u16*   QKB  = (u16*)  (ws + alloc((size_t)NTOK*640*2));   // bf16 concat; later Qp [TTOK][512]
  u16*   QKRW = (u16*)  (ws + alloc((size_t)NTOK*640*2));   // reweighted; later attn-out
  u16*   QKC  = (u16*)  (ws + alloc((size_t)512*640*2));    // conv-k tokens (normalized)
  u16*   XC   = (u16*)  (ws + alloc((size_t)512*512*2));    // conv-v tokens (normalized)
  u16*   KP   = (u16*)  (ws + alloc((size_t)TTOK*512*2));
  u16*   VT   = (u16*)  (ws + alloc((size_t)512*TTOK*2));   // V^T: [h*64+d][tok]
  float* SQm  = (float*)(ws + alloc((size_t)TTOK*4));       // qk-row LN stats
  float* SQs  = (float*)(ws + alloc((size_t)TTOK*4));
  float* SVm  = (float*)(ws + alloc((size_t)TTOK*4));       // x-row LN stats
  float* SVs  = (float*)(ws + alloc((size_t)TTOK*4));
  (void)in_sizes; (void)n_in; (void)out_size; (void)ws_size;

  prep_weights<<<6208, 256, 0, stream>>>(rww, wq, wk, wv, wo, qng, kng, vng,
                                         W_RW, W_QK, W_V, W_O);
  prep_bias<<<6, 256, 0, stream>>>(wq, bq, qnb, qng, wk, bk, knb, kng,
                                   wv, bv, vnb, vng, B_QK, B_V, WS_QK, WS_V);
  build_qk<<<20480, 256, 0, stream>>>(X, F, QKB);

  // reweight: qk_rw = qk * sigmoid(qk @ rw_w^T + rw_b)
  gemm_kernel<1,false><<<1280, 256, 0, stream>>>(QKB, 640, nullptr, 0, W_RW, rwb,
      nullptr, nullptr, nullptr, QKRW, nullptr, nullptr, 640, 640);

  // LN stats (LN itself folded into GEMM epilogues)
  row_stats<640><<<2048, 256, 0, stream>>>(QKRW, 640, SQm, SQs);
  row_stats<512><<<2048, 256, 0, stream>>>(QKB, 640, SVm, SVs);
  convk_ln_kernel<<<512, 640, 0, stream>>>(QKRW, ckw, ckb, QKC, SQm, SQs);
  convv_ln_kernel<<<512, 512, 0, stream>>>(X, cvw, cvb, XC, SVm, SVs);

  // V projection first (reads QKB cols 0..511), transposed epilogue
  gemm_kernel<3,true><<<1040, 256, 0, stream>>>(QKB, 640, XC, 512, W_V, B_V,
      WS_V, SVm, SVs, VT, nullptr, nullptr, 512, 512);
  // merged Q+K projection (N=1024); Q output overwrites QKB
  gemm_kernel<4,true><<<2080, 256, 0, stream>>>(QKRW, 640, QKC, 640, W_QK, B_QK,
      WS_QK, SQm, SQs, QKB, KP, nullptr, 1024, 640);

  attn_kernel<<<4096, 256, 0, stream>>>(QKB, KP, VT, QKRW);

  // output projection -> f32 d_out
  gemm_kernel<2,false><<<1024, 256, 0, stream>>>(QKRW, 512, nullptr, 0, W_O, bo,
      nullptr, nullptr, nullptr, nullptr, nullptr, OutF, 512, 512);
}

// Round 4
// 449.618 us; speedup vs baseline: 1.1744x; 1.0151x over previous
//
#include <hip/hip_runtime.h>

typedef unsigned short u16;
typedef __attribute__((ext_vector_type(8))) short s8v;
typedef __attribute__((ext_vector_type(4))) short s4v;
typedef __attribute__((ext_vector_type(4))) float f4v;

// H=W=64, WS=8, D=512, CF=128, INC=640, HEAD=8, DH=64
#define NTOK 32768
#define TTOK 33280   // 32768 window + 512 global tokens

__device__ __forceinline__ float bf2f(u16 u){
  union { unsigned int i; float f; } p; p.i = ((unsigned int)u) << 16; return p.f;
}
__device__ __forceinline__ u16 f2bf(float f){   // RNE
  union { float f; unsigned int i; } p; p.f = f;
  unsigned int r = p.i + 0x7FFFu + ((p.i >> 16) & 1u);
  return (u16)(r >> 16);
}
__device__ __forceinline__ int wtok_idx(int b, int gh, int gw, int n){
  return b*4096 + (gh*8 + (n>>3))*64 + gw*8 + (n&7);
}
// async global->LDS, 16B per lane; dest is wave-uniform base (HW adds lane*16)
__device__ __forceinline__ void gload16(const u16* g, u16* l){
  __builtin_amdgcn_global_load_lds(
      (const __attribute__((address_space(1))) void*)g,
      (__attribute__((address_space(3))) void*)l, 16, 0, 0);
}

// ---------------- weight prep: bf16 convert + LN-gain fold ----------------
// W_QK is [1024][640]: rows 0..511 = wq*qng, rows 512..1023 = wk*kng
__global__ __launch_bounds__(256) void prep_weights(
    const float* __restrict__ rww, const float* __restrict__ wq,
    const float* __restrict__ wk,  const float* __restrict__ wv,
    const float* __restrict__ wo,  const float* __restrict__ qng,
    const float* __restrict__ kng, const float* __restrict__ vng,
    u16* __restrict__ orw, u16* __restrict__ oqk,
    u16* __restrict__ ov,  u16* __restrict__ oo)
{
  int i = blockIdx.x*256 + threadIdx.x;
  if (i < 409600){ orw[i] = f2bf(rww[i]); return; }
  i -= 409600;
  if (i < 327680){ oqk[i] = f2bf(wq[i] * qng[i % 640]); return; }
  i -= 327680;
  if (i < 327680){ oqk[327680 + i] = f2bf(wk[i] * kng[i % 640]); return; }
  i -= 327680;
  if (i < 262144){ ov[i] = f2bf(wv[i] * vng[i & 511]); return; }
  i -= 262144;
  oo[i] = f2bf(wo[i]);
}

// bias fold b'_o = b_o + sum_i ln_b[i]*W[o,i], and wsum_o = sum_i W'[o,i]
// wave-parallel: 16 lanes per output o; grid 96 x 256
__global__ __launch_bounds__(256) void prep_bias(
    const float* __restrict__ wq, const float* __restrict__ bq,
    const float* __restrict__ qnb, const float* __restrict__ qng,
    const float* __restrict__ wk, const float* __restrict__ bk,
    const float* __restrict__ knb, const float* __restrict__ kng,
    const float* __restrict__ wv, const float* __restrict__ bv,
    const float* __restrict__ vnb, const float* __restrict__ vng,
    float* __restrict__ obqk, float* __restrict__ obv,
    float* __restrict__ owsqk, float* __restrict__ owsv)
{
  int o = blockIdx.x*16 + (threadIdx.x >> 4);  // 0..1535
  int l = threadIdx.x & 15;
  int which = o >> 9, oo = o & 511;
  const float *W, *LB, *LG, *BS; int KK; float *OB, *OWS; int oidx;
  if (which == 0){ W=wq; LB=qnb; LG=qng; BS=bq; KK=640; OB=obqk; OWS=owsqk; oidx=oo; }
  else if (which == 1){ W=wk; LB=knb; LG=kng; BS=bk; KK=640; OB=obqk; OWS=owsqk; oidx=512+oo; }
  else { W=wv; LB=vnb; LG=vng; BS=bv; KK=512; OB=obv; OWS=owsv; oidx=oo; }
  float s = 0.f, ws = 0.f;
  for (int i=l; i<KK; i+=16){
    float w = W[(size_t)oo*KK + i];
    s += LB[i]*w;
    ws += w*LG[i];
  }
  #pragma unroll
  for (int m=1;m<16;m<<=1){ s += __shfl_xor(s,m); ws += __shfl_xor(ws,m); }
  if (l == 0){ OB[oidx] = s + BS[oo]; OWS[oidx] = ws; }
}

// ---------------- build qk = concat(x,f) bf16 + x-row LN stats + zero SQ sums --
// 16 lanes per token; grid 2048 x 256
__global__ __launch_bounds__(256) void build_qk(
    const float* __restrict__ X, const float* __restrict__ F, u16* __restrict__ qkb,
    float* __restrict__ svm, float* __restrict__ svs,
    float* __restrict__ sqs, float* __restrict__ sqs2)
{
  int blk = blockIdx.x;
  int t = blk*16 + (threadIdx.x >> 4);
  int l = threadIdx.x & 15;
  const float* xrow = X + (size_t)t*512;
  u16* orow = qkb + (size_t)t*640;
  float s = 0.f, s2 = 0.f;
  #pragma unroll
  for (int p=0;p<8;p++){
    f4v v = *(const f4v*)(xrow + (p*16+l)*4);
    s4v ov;
    #pragma unroll
    for (int j=0;j<4;j++){
      u16 r = f2bf(v[j]);
      ov[j] = (short)r;
      float rf = bf2f(r);
      s += rf; s2 += rf*rf;
    }
    *(s4v*)(orow + (p*16+l)*4) = ov;
  }
  const float* frow = F + (size_t)t*128;
  #pragma unroll
  for (int p=0;p<2;p++){
    f4v v = *(const f4v*)(frow + (p*16+l)*4);
    s4v ov;
    #pragma unroll
    for (int j=0;j<4;j++) ov[j] = (short)f2bf(v[j]);
    *(s4v*)(orow + 512 + (p*16+l)*4) = ov;
  }
  #pragma unroll
  for (int m=1;m<16;m<<=1){ s += __shfl_xor(s,m); s2 += __shfl_xor(s2,m); }
  if (l == 0){
    float mean = s*(1.f/512.f);
    float var = s2*(1.f/512.f) - mean*mean;
    svm[t] = mean; svs[t] = rsqrtf(var + 1e-5f);
  }
  // zero SQ partial-sum arrays for window rows (re-poisoned each launch)
  int tid = threadIdx.x;
  if (tid < 16) sqs[blk*16 + tid] = 0.f;
  else if (tid < 32) sqs2[blk*16 + (tid-16)] = 0.f;
}

// ---------------- GEMM: C[M,N] = A[M,K](bf16) * W[N,K](bf16)^T ----------------
// A rows >= NTOK come from A2 (conv tokens, pre-normalized).
// SMODE 0: plain bias. 1: stats = (mean, rstd) arrays. 2: stats = (sum, sumsq)/640.
// EPI 1: reweight out0 = bf(A)*sigmoid(acc+bias), accumulates row sums -> sacc
// EPI 2: outf_f32 = acc + bias
// EPI 3: VT transposed: out0[col*TTOK + row]
// EPI 4: QK split: col<512 -> out0 (Q), else out1 (K)
template<int EPI, int SMODE>
__global__ __launch_bounds__(256, 4) void gemm_kernel(
    const u16* __restrict__ A, int strideA,
    const u16* __restrict__ A2, int strideA2,
    const u16* __restrict__ B, const float* __restrict__ bias,
    const float* __restrict__ wsum,
    const float* __restrict__ st0, const float* __restrict__ st1,
    float* __restrict__ sacc0, float* __restrict__ sacc1,
    u16* __restrict__ out0, u16* __restrict__ out1, float* __restrict__ outf,
    int N, int K)
{
  __shared__ u16 lA[128*64];
  __shared__ u16 lB[128*64];
  const int tid = threadIdx.x;
  const int lane = tid & 63;
  const int w = tid >> 6;
  const int wm = (w >> 1) * 64;
  const int wn = (w & 1) * 64;
  const int nb = N >> 7;
  // bijective XCD swizzle (grid %8 == 0)
  const int nwg = (int)gridDim.x;
  const int wg = ((int)blockIdx.x & 7) * (nwg >> 3) + ((int)blockIdx.x >> 3);
  const int m0 = (wg / nb) << 7;
  const int n0 = (wg % nb) << 7;
  const int wbase = tid & ~63;          // wave-uniform slot base

  const f4v fzero = {0.f, 0.f, 0.f, 0.f};
  f4v acc[4][4];
  #pragma unroll
  for (int i=0;i<4;i++)
    #pragma unroll
    for (int j=0;j<4;j++) acc[i][j] = fzero;

  for (int k0 = 0; k0 < K; k0 += 64){
    // async stage: linear LDS dest, source chunk pre-swizzled (cs = cc ^ row&7)
    #pragma unroll
    for (int it=0; it<4; it++){
      int s = it*256 + tid;
      int row = s >> 3, cc = s & 7, cs = cc ^ (row & 7);
      int rr = m0 + row;
      const u16* aptr = (rr < NTOK)
          ? A  + (size_t)rr*strideA  + k0 + cs*8
          : A2 + (size_t)(rr - NTOK)*strideA2 + k0 + cs*8;
      gload16(aptr, &lA[(it*256 + wbase)*8]);
      gload16(B + (size_t)(n0+row)*K + k0 + cs*8, &lB[(it*256 + wbase)*8]);
    }
    __syncthreads();
    #pragma unroll
    for (int kk=0; kk<2; kk++){
      const int cg = kk*4 + (lane>>4);
      s8v bfr[4];
      #pragma unroll
      for (int ni=0; ni<4; ni++){
        int col = wn + ni*16 + (lane&15);
        bfr[ni] = *(const s8v*)&lB[(col*8 + (cg ^ (col&7)))*8];
      }
      #pragma unroll
      for (int mi=0; mi<4; mi++){
        int row = wm + mi*16 + (lane&15);
        s8v afr = *(const s8v*)&lA[(row*8 + (cg ^ (row&7)))*8];
        #pragma unroll
        for (int ni=0; ni<4; ni++)
          acc[mi][ni] = __builtin_amdgcn_mfma_f32_16x16x32_bf16(afr, bfr[ni], acc[mi][ni], 0, 0, 0);
      }
    }
    __syncthreads();
  }

  if constexpr (EPI == 1){
    // reweight + row-stat accumulation (sums of the rounded bf16 outputs)
    #pragma unroll
    for (int mi=0; mi<4; mi++){
      #pragma unroll
      for (int j=0;j<4;j++){
        const int rowg = m0 + wm + mi*16 + (lane>>4)*4 + j;
        float t = 0.f, t2 = 0.f;
        #pragma unroll
        for (int ni=0; ni<4; ni++){
          const int colg = n0 + wn + ni*16 + (lane&15);
          float v = acc[mi][ni][j] + bias[colg];
          float sg = 1.f / (1.f + __expf(-v));
          float qv = bf2f(A[(size_t)rowg*640 + colg]);
          u16 r = f2bf(qv * sg);
          out0[(size_t)rowg*640 + colg] = r;
          float rf = bf2f(r);
          t += rf; t2 += rf*rf;
        }
        #pragma unroll
        for (int m=1;m<16;m<<=1){ t += __shfl_xor(t,m); t2 += __shfl_xor(t2,m); }
        if ((lane & 15) == 0){
          atomicAdd(&sacc0[rowg], t);
          atomicAdd(&sacc1[rowg], t2);
        }
      }
    }
    return;
  }

  #pragma unroll
  for (int mi=0; mi<4; mi++){
    float rs[4], rm[4];
    if constexpr (SMODE == 1){
      #pragma unroll
      for (int j=0;j<4;j++){
        int rowg = m0 + wm + mi*16 + (lane>>4)*4 + j;
        rm[j] = st0[rowg]; rs[j] = st1[rowg];
      }
    } else if constexpr (SMODE == 2){
      #pragma unroll
      for (int j=0;j<4;j++){
        int rowg = m0 + wm + mi*16 + (lane>>4)*4 + j;
        float ss = st0[rowg], ss2 = st1[rowg];
        float mean = ss*(1.f/640.f);
        float var = ss2*(1.f/640.f) - mean*mean;
        rm[j] = mean; rs[j] = rsqrtf(var + 1e-5f);
      }
    }
    #pragma unroll
    for (int ni=0; ni<4; ni++){
      const int colg = n0 + wn + ni*16 + (lane&15);
      const float bb = bias[colg];
      const float wsc = (SMODE != 0) ? wsum[colg] : 0.f;
      if constexpr (EPI == 3){
        const int rowg0 = m0 + wm + mi*16 + (lane>>4)*4;
        s4v pk;
        #pragma unroll
        for (int j=0;j<4;j++){
          float v = (SMODE != 0) ? (rs[j]*acc[mi][ni][j] - rs[j]*rm[j]*wsc + bb)
                                 : (acc[mi][ni][j] + bb);
          pk[j] = (short)f2bf(v);
        }
        *(s4v*)(out0 + (size_t)colg*TTOK + rowg0) = pk;
      } else {
        #pragma unroll
        for (int j=0;j<4;j++){
          const int rowg = m0 + wm + mi*16 + (lane>>4)*4 + j;
          float v = (SMODE != 0) ? (rs[j]*acc[mi][ni][j] - rs[j]*rm[j]*wsc + bb)
                                 : (acc[mi][ni][j] + bb);
          if constexpr (EPI == 2){
            outf[(size_t)rowg*512 + colg] = v;
          } else { // EPI 4
            if (colg < 512) out0[(size_t)rowg*512 + colg] = f2bf(v);
            else            out1[(size_t)rowg*512 + (colg-512)] = f2bf(v);
          }
        }
      }
    }
  }
}

// ---------------- merged depthwise 8x8 stride-8 convs + LN ----------------
// all 640 threads: conv-k from reweighted qk; threads <512 also conv-v from X
__global__ __launch_bounds__(640) void conv_ln_kernel(
    const u16* __restrict__ qkrw, const float* __restrict__ X,
    const float* __restrict__ ckw, const float* __restrict__ ckb,
    const float* __restrict__ cvw, const float* __restrict__ cvb,
    u16* __restrict__ qkc, u16* __restrict__ xc,
    float* __restrict__ sqs, float* __restrict__ sqs2,
    float* __restrict__ svm, float* __restrict__ svs)
{
  int bg = blockIdx.x;               // b*64 + gpos
  int b = bg >> 6, gpos = bg & 63;
  int gh = gpos >> 3, gw = gpos & 7;
  int ch = threadIdx.x;              // 0..639
  int base = b*4096 + gh*8*64 + gw*8;

  float acck = ckb[ch];
  #pragma unroll
  for (int r=0;r<8;r++)
    #pragma unroll
    for (int c=0;c<8;c++)
      acck += bf2f(qkrw[(size_t)(base + r*64 + c)*640 + ch]) * ckw[ch*64 + r*8 + c];

  float accv = 0.f;
  if (ch < 512){
    accv = cvb[ch];
    #pragma unroll
    for (int r=0;r<8;r++)
      #pragma unroll
      for (int c=0;c<8;c++)
        accv += X[(size_t)(base + r*64 + c)*512 + ch] * cvw[ch*64 + r*8 + c];
  }

  int wid = threadIdx.x >> 6, lane = threadIdx.x & 63;
  float sk = acck, sk2 = acck*acck;
  float sv = accv, sv2 = accv*accv;
  #pragma unroll
  for (int m=1;m<64;m<<=1){
    sk += __shfl_xor(sk,m); sk2 += __shfl_xor(sk2,m);
    sv += __shfl_xor(sv,m); sv2 += __shfl_xor(sv2,m);
  }
  __shared__ float rk[10], rk2[10], rv[8], rv2[8];
  if (lane == 0){
    rk[wid] = sk; rk2[wid] = sk2;
    if (wid < 8){ rv[wid] = sv; rv2[wid] = sv2; }
  }
  __syncthreads();
  float tk = 0.f, tk2 = 0.f;
  #pragma unroll
  for (int i=0;i<10;i++){ tk += rk[i]; tk2 += rk2[i]; }
  float meank = tk*(1.f/640.f);
  float vark = tk2*(1.f/640.f) - meank*meank;
  float rstdk = rsqrtf(vark + 1e-5f);
  qkc[(size_t)bg*640 + ch] = f2bf((acck-meank)*rstdk);

  if (ch < 512){
    float tv = 0.f, tv2 = 0.f;
    #pragma unroll
    for (int i=0;i<8;i++){ tv += rv[i]; tv2 += rv2[i]; }
    float meanv = tv*(1.f/512.f);
    float varv = tv2*(1.f/512.f) - meanv*meanv;
    float rstdv = rsqrtf(varv + 1e-5f);
    xc[(size_t)bg*512 + ch] = f2bf((accv-meanv)*rstdv);
  }
  if (ch == 0){
    sqs[NTOK + bg] = 0.f;
    sqs2[NTOK + bg] = 640.f*(1.f - 1e-5f);  // -> var+eps = 1 exactly
    svm[NTOK + bg] = 0.f;
    svs[NTOK + bg] = 1.f;
  }
}

// ---------------- attention: direct-global fragments, P-only LDS ----------
__global__ __launch_bounds__(256, 3) void attn_kernel(
    const u16* __restrict__ Qp, const u16* __restrict__ Kp,
    const u16* __restrict__ VT, u16* __restrict__ Out)
{
  int blk = blockIdx.x;                 // b*512 + g*8 + h
  int h = blk & 7, g = (blk >> 3) & 63, b = blk >> 9;
  int gh = g >> 3, gw = g & 7;
  int tid = threadIdx.x, lane = tid & 63, wvid = tid >> 6;
  int l15 = lane & 15, lg = lane >> 4;

  __shared__ u16 ps[64*128];   // P: [q][ktok], 16 chunks/row, swz ^(q&15)
  __shared__ float red[4][64];

  s8v qf[4][2], kf[2][2], vf[4];
  #pragma unroll
  for (int mi=0; mi<4; mi++){
    const u16* qrow = Qp + (size_t)wtok_idx(b,gh,gw, mi*16 + l15)*512 + h*64;
    #pragma unroll
    for (int kk=0; kk<2; kk++)
      qf[mi][kk] = *(const s8v*)(qrow + (kk*4+lg)*8);
  }
  #pragma unroll
  for (int ni=0; ni<2; ni++){
    int kt = wvid*32 + ni*16 + l15;
    int tok = (kt < 64) ? wtok_idx(b,gh,gw,kt) : (NTOK + b*64 + (kt-64));
    const u16* krow = Kp + (size_t)tok*512 + h*64;
    #pragma unroll
    for (int kk=0; kk<2; kk++)
      kf[ni][kk] = *(const s8v*)(krow + (kk*4+lg)*8);
  }
  {
    int d = wvid*16 + l15;
    const u16* vrow = VT + (size_t)(h*64 + d)*TTOK;
    #pragma unroll
    for (int c4=0; c4<4; c4++){
      int kt0 = (c4*4+lg)*8;
      int tok0 = (kt0 < 64) ? wtok_idx(b,gh,gw,kt0) : (NTOK + b*64 + (kt0-64));
      vf[c4] = *(const s8v*)(vrow + tok0);   // 8 consecutive tokens
    }
  }

  const f4v fzero = {0.f,0.f,0.f,0.f};
  f4v sacc[4][2];
  #pragma unroll
  for (int i=0;i<4;i++){ sacc[i][0]=fzero; sacc[i][1]=fzero; }
  #pragma unroll
  for (int kk=0; kk<2; kk++)
    #pragma unroll
    for (int mi=0; mi<4; mi++)
      #pragma unroll
      for (int ni=0; ni<2; ni++)
        sacc[mi][ni] = __builtin_amdgcn_mfma_f32_16x16x32_bf16(qf[mi][kk], kf[ni][kk], sacc[mi][ni], 0,0,0);

  float psum[4][4];
  #pragma unroll
  for (int mi=0; mi<4; mi++){
    #pragma unroll
    for (int j=0;j<4;j++){
      float e0 = __expf(sacc[mi][0][j] * 0.125f);
      float e1 = __expf(sacc[mi][1][j] * 0.125f);
      sacc[mi][0][j] = e0; sacc[mi][1][j] = e1;
      float t0 = e0 + e1;
      #pragma unroll
      for (int m=1;m<16;m<<=1) t0 += __shfl_xor(t0, m);
      psum[mi][j] = t0;
    }
  }
  if (l15 == 0){
    #pragma unroll
    for (int mi=0; mi<4; mi++)
      #pragma unroll
      for (int j=0;j<4;j++)
        red[wvid][mi*16 + lg*4 + j] = psum[mi][j];
  }
  __syncthreads();

  #pragma unroll
  for (int mi=0; mi<4; mi++){
    #pragma unroll
    for (int j=0;j<4;j++){
      int r = mi*16 + lg*4 + j;
      float inv = 1.0f / (red[0][r] + red[1][r] + red[2][r] + red[3][r]);
      #pragma unroll
      for (int ni=0; ni<2; ni++){
        int col = wvid*32 + ni*16 + l15;
        int ck = (col >> 3) ^ (r & 15);
        ps[r*128 + ck*8 + (col & 7)] = f2bf(sacc[mi][ni][j] * inv);
      }
    }
  }
  __syncthreads();

  f4v oacc[4];
  #pragma unroll
  for (int i=0;i<4;i++) oacc[i] = fzero;
  #pragma unroll
  for (int c4=0; c4<4; c4++){
    int cg = c4*4 + lg;
    #pragma unroll
    for (int mi=0; mi<4; mi++){
      s8v afr = *(const s8v*)&ps[((mi*16 + l15)*16 + (cg ^ l15))*8];
      oacc[mi] = __builtin_amdgcn_mfma_f32_16x16x32_bf16(afr, vf[c4], oacc[mi], 0,0,0);
    }
  }
  #pragma unroll
  for (int mi=0; mi<4; mi++)
    #pragma unroll
    for (int j=0;j<4;j++){
      int q = mi*16 + lg*4 + j;
      Out[(size_t)wtok_idx(b,gh,gw,q)*512 + h*64 + wvid*16 + l15] = f2bf(oacc[mi][j]);
    }
}

// ---------------- launcher ----------------
extern "C" void kernel_launch(void* const* d_in, const int* in_sizes, int n_in,
                              void* d_out, int out_size, void* d_ws, size_t ws_size,
                              hipStream_t stream)
{
  const float* X   = (const float*)d_in[0];
  const float* F   = (const float*)d_in[1];
  const float* wq  = (const float*)d_in[2];
  const float* bq  = (const float*)d_in[3];
  const float* wk  = (const float*)d_in[4];
  const float* bk  = (const float*)d_in[5];
  const float* wv  = (const float*)d_in[6];
  const float* bv  = (const float*)d_in[7];
  const float* wo  = (const float*)d_in[8];
  const float* bo  = (const float*)d_in[9];
  const float* rww = (const float*)d_in[10];
  const float* rwb = (const float*)d_in[11];
  const float* ckw = (const float*)d_in[12];
  const float* ckb = (const float*)d_in[13];
  const float* cvw = (const float*)d_in[14];
  const float* cvb = (const float*)d_in[15];
  const float* qng = (const float*)d_in[16];
  const float* qnb = (const float*)d_in[17];
  const float* kng = (const float*)d_in[18];
  const float* knb = (const float*)d_in[19];
  const float* vng = (const float*)d_in[20];
  const float* vnb = (const float*)d_in[21];
  float* OutF = (float*)d_out;

  char* ws = (char*)d_ws;
  size_t off = 0;
  auto alloc = [&](size_t bytes){
    size_t o = off; off += (bytes + 255) & ~(size_t)255; return o;
  };
  u16*   W_RW = (u16*)  (ws + alloc((size_t)640*640*2));
  u16*   W_QK = (u16*)  (ws + alloc((size_t)1024*640*2));
  u16*   W_V  = (u16*)  (ws + alloc((size_t)512*512*2));
  u16*   W_O  = (u16*)  (ws + alloc((size_t)512*512*2));
  float* B_QK = (float*)(ws + alloc(1024*4));
  float* B_V  = (float*)(ws + alloc(512*4));
  float* WS_QK= (float*)(ws + alloc(1024*4));
  float* WS_V = (float*)(ws + alloc(512*4));
  u16*   QKB  = (u16*)  (ws + alloc((size_t)NTOK*640*2));   // bf16 concat; later Qp
  u16*   QKRW = (u16*)  (ws + alloc((size_t)NTOK*640*2));   // reweighted; later attn-out
  u16*   QKC  = (u16*)  (ws + alloc((size_t)512*640*2));    // conv-k tokens (normalized)
  u16*   XC   = (u16*)  (ws + alloc((size_t)512*512*2));    // conv-v tokens (normalized)
  u16*   KP   = (u16*)  (ws + alloc((size_t)TTOK*512*2));
  u16*   VT   = (u16*)  (ws + alloc((size_t)512*TTOK*2));   // V^T: [h*64+d][tok]
  float* SQs0 = (float*)(ws + alloc((size_t)TTOK*4));       // qk-row sum
  float* SQs1 = (float*)(ws + alloc((size_t)TTOK*4));       // qk-row sumsq
  float* SVm  = (float*)(ws + alloc((size_t)TTOK*4));       // x-row mean
  float* SVs  = (float*)(ws + alloc((size_t)TTOK*4));       // x-row rstd
  (void)in_sizes; (void)n_in; (void)out_size; (void)ws_size;

  prep_weights<<<6208, 256, 0, stream>>>(rww, wq, wk, wv, wo, qng, kng, vng,
                                         W_RW, W_QK, W_V, W_O);
  prep_bias<<<96, 256, 0, stream>>>(wq, bq, qnb, qng, wk, bk, knb, kng,
                                    wv, bv, vnb, vng, B_QK, B_V, WS_QK, WS_V);
  build_qk<<<2048, 256, 0, stream>>>(X, F, QKB, SVm, SVs, SQs0, SQs1);

  // reweight: qk_rw = qk * sigmoid(qk @ rw_w^T + rw_b); accumulates SQ row sums
  gemm_kernel<1,0><<<1280, 256, 0, stream>>>(QKB, 640, nullptr, 0, W_RW, rwb,
      nullptr, nullptr, nullptr, SQs0, SQs1, QKRW, nullptr, nullptr, 640, 640);

  conv_ln_kernel<<<512, 640, 0, stream>>>(QKRW, X, ckw, ckb, cvw, cvb,
      QKC, XC, SQs0, SQs1, SVm, SVs);

  // V projection (LN folded via SVm/SVs), transposed epilogue
  gemm_kernel<3,1><<<1040, 256, 0, stream>>>(QKB, 640, XC, 512, W_V, B_V,
      WS_V, SVm, SVs, nullptr, nullptr, VT, nullptr, nullptr, 512, 512);
  // merged Q+K projection (LN folded via SQ sums); Q overwrites QKB
  gemm_kernel<4,2><<<2080, 256, 0, stream>>>(QKRW, 640, QKC, 640, W_QK, B_QK,
      WS_QK, SQs0, SQs1, nullptr, nullptr, QKB, KP, nullptr, 1024, 640);

  attn_kernel<<<4096, 256, 0, stream>>>(QKB, KP, VT, QKRW);

  // output projection -> f32 d_out
  gemm_kernel<2,0><<<1024, 256, 0, stream>>>(QKRW, 512, nullptr, 0, W_O, bo,
      nullptr, nullptr, nullptr, nullptr, nullptr, nullptr, nullptr, OutF, 512, 512);
}